// Round 12
// baseline (474.566 us; speedup 1.0000x reference)
//
#include <hip/hip_runtime.h>

#define N_NODES 100000
#define N_PAD   100352        // 392*256
#define N_EDGES 3200000
#define IN_DIM  128
#define HID     64
#define N_GRAPHS 256
#define NB      392           // buckets of 256 dest nodes each
#define NBLK    256           // hist/scatter blocks
#define EPB     (N_EDGES / NBLK)   // 12500

typedef unsigned short ushort_t;
typedef unsigned int   uint_t;

// bf16 helpers: storage-only compression of the gathered operand
__device__ __forceinline__ ushort_t f2bf(float v) {          // round-to-nearest-even
    uint_t b = __float_as_uint(v);
    b += 0x7fffu + ((b >> 16) & 1u);
    return (ushort_t)(b >> 16);
}
__device__ __forceinline__ void bf2f2(uint_t u, float& lo, float& hi) {
    lo = __uint_as_float(u << 16);
    hi = __uint_as_float(u & 0xffff0000u);
}
// 16B load -> 8 floats
__device__ __forceinline__ void ld_bf16x8(const ushort_t* p, float4& a, float4& b) {
    uint4 u = *(const uint4*)p;
    bf2f2(u.x, a.x, a.y); bf2f2(u.y, a.z, a.w);
    bf2f2(u.z, b.x, b.y); bf2f2(u.w, b.z, b.w);
}

// ---------- phase 1: per-block bucket histogram (dual LDS tables, no global atomics) ----
__global__ __launch_bounds__(256) void bhist_kernel(const int* __restrict__ col,
                                                    int* __restrict__ H) {
    __shared__ int h[2][NB];
    for (int i = threadIdx.x; i < NB; i += 256) { h[0][i] = 0; h[1][i] = 0; }
    __syncthreads();
    const int4* col4 = (const int4*)col;
    int base4 = blockIdx.x * (EPB / 4);
    int sel = threadIdx.x & 1;
    for (int j = threadIdx.x; j < EPB / 4; j += 256) {
        int4 c = col4[base4 + j];
        atomicAdd(&h[sel][c.x >> 8], 1);
        atomicAdd(&h[sel][c.y >> 8], 1);
        atomicAdd(&h[sel][c.z >> 8], 1);
        atomicAdd(&h[sel][c.w >> 8], 1);
    }
    __syncthreads();
    for (int i = threadIdx.x; i < NB; i += 256) H[i * NBLK + blockIdx.x] = h[0][i] + h[1][i];
}

// ---------- phase 2: exclusive scan of H (NB*NBLK, bucket-major) ----------
__global__ __launch_bounds__(256) void scan1_kernel(int* H, int* __restrict__ bsum) {
    __shared__ int s[256];
    int i = blockIdx.x * 256 + threadIdx.x;   // blockIdx.x == bucket (NBLK==256)
    int v = H[i];
    s[threadIdx.x] = v;
    __syncthreads();
    #pragma unroll
    for (int off = 1; off < 256; off <<= 1) {
        int t = (threadIdx.x >= off) ? s[threadIdx.x - off] : 0;
        __syncthreads();
        s[threadIdx.x] += t;
        __syncthreads();
    }
    H[i] = s[threadIdx.x] - v;                           // exclusive within bucket
    if (threadIdx.x == 255) bsum[blockIdx.x] = s[255];   // bucket total
}

// ---------- phase 3: scatter records; bucket-offset scan (old scan2) folded in ----------
// rec = (row | local<<17, ew); local = col & 255 (8 bits), row < 2^17
__global__ __launch_bounds__(256) void bscatter_kernel(const int* __restrict__ row,
                                                       const int* __restrict__ col,
                                                       const float* __restrict__ ew,
                                                       const int* __restrict__ H,
                                                       const int* __restrict__ bsum,
                                                       int* __restrict__ boff,
                                                       int2* __restrict__ recs) {
    __shared__ int cur[NB];
    __shared__ int tboff[NB];
    __shared__ int s[256];
    __shared__ int carry;
    int tid = threadIdx.x;
    if (tid == 0) carry = 0;
    __syncthreads();
    // local exclusive scan of bsum[0..NB) -> tboff (every block does it; ~1 us)
    for (int c = 0; c < (NB + 255) / 256; ++c) {
        int i = c * 256 + tid;
        int v = (i < NB) ? bsum[i] : 0;
        s[tid] = v;
        __syncthreads();
        #pragma unroll
        for (int off = 1; off < 256; off <<= 1) {
            int t = (tid >= off) ? s[tid - off] : 0;
            __syncthreads();
            s[tid] += t;
            __syncthreads();
        }
        if (i < NB) tboff[i] = s[tid] - v + carry;
        __syncthreads();
        if (tid == 0) carry += s[255];
        __syncthreads();
    }
    for (int i = tid; i < NB; i += 256)
        cur[i] = H[i * NBLK + blockIdx.x] + tboff[i];
    if (blockIdx.x == 0)                      // publish boff for later kernels
        for (int i = tid; i < NB; i += 256) boff[i] = tboff[i];
    __syncthreads();
    const int4*   row4 = (const int4*)row;
    const int4*   col4 = (const int4*)col;
    const float4* ew4  = (const float4*)ew;
    int base4 = blockIdx.x * (EPB / 4);
    for (int j = tid; j < EPB / 4; j += 256) {
        int4   r4 = row4[base4 + j];
        int4   c4 = col4[base4 + j];
        float4 w4 = ew4[base4 + j];
        int p0 = atomicAdd(&cur[c4.x >> 8], 1);
        recs[p0] = make_int2(r4.x | ((c4.x & 255) << 17), __float_as_int(w4.x));
        int p1 = atomicAdd(&cur[c4.y >> 8], 1);
        recs[p1] = make_int2(r4.y | ((c4.y & 255) << 17), __float_as_int(w4.y));
        int p2 = atomicAdd(&cur[c4.z >> 8], 1);
        recs[p2] = make_int2(r4.z | ((c4.z & 255) << 17), __float_as_int(w4.z));
        int p3 = atomicAdd(&cur[c4.w >> 8], 1);
        recs[p3] = make_int2(r4.w | ((c4.w & 255) << 17), __float_as_int(w4.w));
    }
}

// ---------- phase 3.5: ONE recs pass -> deg + cnt; writes dis AND rowptr ----------
__global__ __launch_bounds__(256) void degcnt_kernel(const int2* __restrict__ recs,
                                                     const int* __restrict__ boff,
                                                     float* __restrict__ dis,
                                                     int* __restrict__ rowptr) {
    __shared__ int   cnt[256];
    __shared__ float degf[256];
    __shared__ int   sscan[256];
    int b = blockIdx.x, tid = threadIdx.x;
    cnt[tid] = 0; degf[tid] = 0.f;
    __syncthreads();
    int s = boff[b], e = (b + 1 < NB) ? boff[b + 1] : N_EDGES;
    for (int j = s + tid; j < e; j += 256) {
        int2 r = recs[j];
        int cl = (r.x >> 17) & 255;
        atomicAdd(&cnt[cl], 1);
        atomicAdd(&degf[cl], __int_as_float(r.y));
    }
    __syncthreads();
    int c = cnt[tid];
    sscan[tid] = c;
    __syncthreads();
    #pragma unroll
    for (int off = 1; off < 256; off <<= 1) {
        int t = (tid >= off) ? sscan[tid - off] : 0;
        __syncthreads();
        sscan[tid] += t;
        __syncthreads();
    }
    rowptr[b * 256 + tid] = s + sscan[tid] - c;   // exclusive; pad nodes get == e
    dis[b * 256 + tid] = 1.0f / sqrtf(fmaxf(1.0f + degf[tid], 1e-30f));
}

// ---------- phase 4: scatter-only CSR write; cursors seeded from rowptr ----------
// csr[pos] = (row, dis[row] * ew * dis[col])
__global__ __launch_bounds__(256) void csrw_kernel(const int2* __restrict__ recs,
                                                   const int* __restrict__ boff,
                                                   const float* __restrict__ dis,
                                                   const int* __restrict__ rowptr,
                                                   float2* __restrict__ csr) {
    __shared__ int   cur[256];
    __shared__ float sdis[256];
    int b = blockIdx.x, tid = threadIdx.x;
    cur[tid]  = rowptr[b * 256 + tid];
    sdis[tid] = dis[b * 256 + tid];
    __syncthreads();
    int s = boff[b], e = (b + 1 < NB) ? boff[b + 1] : N_EDGES;
    for (int j = s + tid; j < e; j += 256) {
        int2 r = recs[j];
        int cl = (r.x >> 17) & 255;
        int rr = r.x & 0x1FFFF;
        int pos = atomicAdd(&cur[cl], 1);
        csr[pos] = make_float2(__int_as_float(rr),
                               dis[rr] * __int_as_float(r.y) * sdis[cl]);
    }
}

// ---------- layer 1 GEMM: xl = x @ W1 (bf16 output), 8 rows/block ----------
__global__ __launch_bounds__(256) void gemm1_kernel(const float* __restrict__ x,
                                                    const float* __restrict__ W1,
                                                    ushort_t* __restrict__ xl) {
    __shared__ float sW[IN_DIM * HID];   // 32 KB
    __shared__ float sx[8][IN_DIM];      // 4 KB
    int tid = threadIdx.x;
    const float4* W4  = (const float4*)W1;
    float4*       sW4 = (float4*)sW;
    #pragma unroll
    for (int i = 0; i < 8; ++i) sW4[tid + 256 * i] = W4[tid + 256 * i];
    int r0 = blockIdx.x * 8;             // grid 12500 exact
    const float4* x4  = (const float4*)(x + (size_t)r0 * IN_DIM);
    float4*       sx4 = (float4*)&sx[0][0];
    sx4[tid] = x4[tid];                  // 256 float4 = 8 rows x 128
    __syncthreads();
    int c = tid & 63;
    #pragma unroll
    for (int rep = 0; rep < 2; ++rep) {
        int lr = (tid >> 6) * 2 + rep;   // 0..7
        float acc = 0.f;
        #pragma unroll 8
        for (int k = 0; k < IN_DIM; ++k) acc += sx[lr][k] * sW[k * HID + c];
        xl[(size_t)(r0 + lr) * HID + c] = f2bf(acc);
    }
}

// ---------- gather core: 8-lane groups, 16B loads, 4 edges in flight/group ----------
// lanes 0..7 hold the final 64-channel row (8 channels each) after reduction
__device__ __forceinline__ void gather_row(const float2* __restrict__ csr,
                                           const ushort_t* __restrict__ xl,
                                           int base, int end, int n, float d2,
                                           int g, int c0,
                                           float4& a0, float4& a1) {
    a0 = make_float4(0.f, 0.f, 0.f, 0.f);
    a1 = make_float4(0.f, 0.f, 0.f, 0.f);
    if (g == 0) {
        float4 s0, s1;
        ld_bf16x8(xl + (size_t)n * HID + c0, s0, s1);
        a0.x = s0.x * d2; a0.y = s0.y * d2; a0.z = s0.z * d2; a0.w = s0.w * d2;
        a1.x = s1.x * d2; a1.y = s1.y * d2; a1.z = s1.z * d2; a1.w = s1.w * d2;
    }
    int j = base + g;
    for (; j + 24 < end; j += 32) {                      // 4 edges in flight
        float2 e0 = csr[j];
        float2 e1 = csr[j + 8];
        float2 e2 = csr[j + 16];
        float2 e3 = csr[j + 24];
        int r0_ = __float_as_int(e0.x), r1_ = __float_as_int(e1.x);
        int r2_ = __float_as_int(e2.x), r3_ = __float_as_int(e3.x);
        float4 xa0, xa1, xb0, xb1, xc0, xc1, xd0, xd1;
        ld_bf16x8(xl + (size_t)r0_ * HID + c0, xa0, xa1);
        ld_bf16x8(xl + (size_t)r1_ * HID + c0, xb0, xb1);
        ld_bf16x8(xl + (size_t)r2_ * HID + c0, xc0, xc1);
        ld_bf16x8(xl + (size_t)r3_ * HID + c0, xd0, xd1);
        a0.x += xa0.x * e0.y + xb0.x * e1.y + xc0.x * e2.y + xd0.x * e3.y;
        a0.y += xa0.y * e0.y + xb0.y * e1.y + xc0.y * e2.y + xd0.y * e3.y;
        a0.z += xa0.z * e0.y + xb0.z * e1.y + xc0.z * e2.y + xd0.z * e3.y;
        a0.w += xa0.w * e0.y + xb0.w * e1.y + xc0.w * e2.y + xd0.w * e3.y;
        a1.x += xa1.x * e0.y + xb1.x * e1.y + xc1.x * e2.y + xd1.x * e3.y;
        a1.y += xa1.y * e0.y + xb1.y * e1.y + xc1.y * e2.y + xd1.y * e3.y;
        a1.z += xa1.z * e0.y + xb1.z * e1.y + xc1.z * e2.y + xd1.z * e3.y;
        a1.w += xa1.w * e0.y + xb1.w * e1.y + xc1.w * e2.y + xd1.w * e3.y;
    }
    for (; j < end; j += 8) {
        float2 e0 = csr[j];
        int ra = __float_as_int(e0.x);
        float w0 = e0.y;
        float4 xa0, xa1;
        ld_bf16x8(xl + (size_t)ra * HID + c0, xa0, xa1);
        a0.x += xa0.x * w0; a0.y += xa0.y * w0; a0.z += xa0.z * w0; a0.w += xa0.w * w0;
        a1.x += xa1.x * w0; a1.y += xa1.y * w0; a1.z += xa1.z * w0; a1.w += xa1.w * w0;
    }
    #pragma unroll
    for (int o = 32; o >= 8; o >>= 1) {
        a0.x += __shfl_down(a0.x, o, 64); a0.y += __shfl_down(a0.y, o, 64);
        a0.z += __shfl_down(a0.z, o, 64); a0.w += __shfl_down(a0.w, o, 64);
        a1.x += __shfl_down(a1.x, o, 64); a1.y += __shfl_down(a1.y, o, 64);
        a1.z += __shfl_down(a1.z, o, 64); a1.w += __shfl_down(a1.w, o, 64);
    }
}

// ---------- fused gather1 + gemm2: xl2 = relu(gather(xl1) + b1) @ W2 (bf16 out) ----------
__global__ __launch_bounds__(256) void gather_gemm2_kernel(
        const float2* __restrict__ csr, const int* __restrict__ rowptr,
        const float* __restrict__ dis, const ushort_t* __restrict__ xl,
        const float* __restrict__ W2, const float* __restrict__ b1,
        ushort_t* __restrict__ xl2) {
    __shared__ float sW[HID * HID];   // 16 KB
    __shared__ float sh[4][HID];
    __shared__ float sb1[HID];
    int tid = threadIdx.x;
    const float4* W4  = (const float4*)W2;
    float4*       sW4 = (float4*)sW;
    #pragma unroll
    for (int i = 0; i < 4; ++i) sW4[tid + 256 * i] = W4[tid + 256 * i];
    if (tid < HID) sb1[tid] = b1[tid];

    int r0   = blockIdx.x * 4;
    int wv   = tid >> 6;
    int n    = r0 + wv;
    int lane = tid & 63;
    int g    = lane >> 3;
    int c0   = (lane & 7) << 3;
    int base = rowptr[n], end = rowptr[n + 1];
    float d  = dis[n];
    float4 a0, a1;
    gather_row(csr, xl, base, end, n, d * d, g, c0, a0, a1);
    if (lane < 8) {
        *(float4*)(&sh[wv][c0])     = a0;
        *(float4*)(&sh[wv][c0 + 4]) = a1;
    }
    __syncthreads();                                    // sW, sb1, sh all visible
    int lr = wv, cc = lane;
    float hv = fmaxf(sh[lr][cc] + sb1[cc], 0.f);        // relu(agg1 + b1)
    __syncthreads();
    sh[lr][cc] = hv;
    __syncthreads();
    float acc2 = 0.f;
    #pragma unroll 8
    for (int k = 0; k < HID; ++k) acc2 += sh[lr][k] * sW[k * HID + cc];
    xl2[(size_t)(r0 + lr) * HID + cc] = f2bf(acc2);
}

// ---------- fused gather2 + pool partial: sval[n] = relu(agg2[n]+b2) . Wc ----------
// coalesced scalar store per node; NO atomics (256-slot atomic target serializes at L2)
__global__ __launch_bounds__(256) void gather_pool_kernel(
        const float2* __restrict__ csr, const int* __restrict__ rowptr,
        const float* __restrict__ dis, const ushort_t* __restrict__ xl,
        const float* __restrict__ b2, const float* __restrict__ Wc,
        float* __restrict__ sval) {
    int tid  = threadIdx.x;
    int n    = (blockIdx.x * 256 + tid) >> 6;           // grid 25000 exact
    int lane = tid & 63;
    int g    = lane >> 3;
    int c0   = (lane & 7) << 3;
    int base = rowptr[n], end = rowptr[n + 1];
    float d  = dis[n];
    float4 a0, a1;
    gather_row(csr, xl, base, end, n, d * d, g, c0, a0, a1);
    if (lane < 8) {
        float4 bb0 = *(const float4*)(b2 + c0);
        float4 bb1 = *(const float4*)(b2 + c0 + 4);
        float4 wc0 = *(const float4*)(Wc + c0);
        float4 wc1 = *(const float4*)(Wc + c0 + 4);
        float s = fmaxf(a0.x + bb0.x, 0.f) * wc0.x + fmaxf(a0.y + bb0.y, 0.f) * wc0.y
                + fmaxf(a0.z + bb0.z, 0.f) * wc0.z + fmaxf(a0.w + bb0.w, 0.f) * wc0.w
                + fmaxf(a1.x + bb1.x, 0.f) * wc1.x + fmaxf(a1.y + bb1.y, 0.f) * wc1.y
                + fmaxf(a1.z + bb1.z, 0.f) * wc1.z + fmaxf(a1.w + bb1.w, 0.f) * wc1.w;
        s += __shfl_down(s, 4, 64);
        s += __shfl_down(s, 2, 64);
        s += __shfl_down(s, 1, 64);
        if (lane == 0) sval[n] = s;
    }
}

// ---------- final: out[g] = mean(sval over graph range) + bc ----------
__global__ __launch_bounds__(256) void final_out_kernel(const float* __restrict__ sval,
                                                        const int* __restrict__ batch,
                                                        const float* __restrict__ bc,
                                                        float* __restrict__ out) {
    __shared__ float s[256];
    int g = blockIdx.x;   // grid N_GRAPHS
    int lo = 0, hi = N_NODES;
    while (lo < hi) { int m = (lo + hi) >> 1; if (batch[m] < g) lo = m + 1; else hi = m; }
    int start = lo;
    hi = N_NODES;
    while (lo < hi) { int m = (lo + hi) >> 1; if (batch[m] < g + 1) lo = m + 1; else hi = m; }
    int end = lo;
    float acc = 0.f;
    for (int i = start + threadIdx.x; i < end; i += 256) acc += sval[i];
    s[threadIdx.x] = acc;
    __syncthreads();
    #pragma unroll
    for (int off = 128; off > 0; off >>= 1) {
        if (threadIdx.x < off) s[threadIdx.x] += s[threadIdx.x + off];
        __syncthreads();
    }
    if (threadIdx.x == 0)
        out[g] = s[0] / fmaxf((float)(end - start), 1.0f) + bc[0];
}

extern "C" void kernel_launch(void* const* d_in, const int* in_sizes, int n_in,
                              void* d_out, int out_size, void* d_ws, size_t ws_size,
                              hipStream_t stream) {
    const float* x     = (const float*)d_in[0];
    const int*   ei    = (const int*)  d_in[1];
    const float* ew    = (const float*)d_in[2];
    const int*   batch = (const int*)  d_in[3];
    const float* W1    = (const float*)d_in[4];
    const float* b1    = (const float*)d_in[5];
    const float* W2    = (const float*)d_in[6];
    const float* b2    = (const float*)d_in[7];
    const float* Wc    = (const float*)d_in[8];
    const float* bc    = (const float*)d_in[9];
    float* out = (float*)d_out;

    const int* row = ei;
    const int* col = ei + N_EDGES;

    // workspace (~78 MB): recs | xlA | xlB | csr | rowptr | dis | bsum | boff | sval
    // H aliases csr (dead before csrw writes csr).
    int2*     recs   = (int2*)d_ws;                              // E int2 = 25.6 MB
    ushort_t* xlA    = (ushort_t*)(recs + N_EDGES);              // N*HID bf16
    ushort_t* xlB    = xlA + (size_t)N_NODES * HID;              // N*HID bf16
    float2*   csr    = (float2*)(xlB + (size_t)N_NODES * HID);   // E float2
    int*      rowptr = (int*)(csr + N_EDGES);                    // N_PAD
    float*    dis    = (float*)(rowptr + N_PAD);                 // N_PAD
    int*      bsum   = (int*)(dis + N_PAD);                      // 512
    int*      boff   = bsum + 512;                               // 512
    float*    sval   = (float*)(boff + 512);                     // N_PAD
    int*      H      = (int*)csr;                                // NB*NBLK ints = 401 KB

    bhist_kernel    <<<NBLK, 256, 0, stream>>>(col, H);
    scan1_kernel    <<<NB,   256, 0, stream>>>(H, bsum);
    bscatter_kernel <<<NBLK, 256, 0, stream>>>(row, col, ew, H, bsum, boff, recs);
    degcnt_kernel   <<<NB,   256, 0, stream>>>(recs, boff, dis, rowptr);
    csrw_kernel     <<<NB,   256, 0, stream>>>(recs, boff, dis, rowptr, csr);
    gemm1_kernel    <<<N_NODES / 8, 256, 0, stream>>>(x, W1, xlA);
    gather_gemm2_kernel<<<N_NODES / 4, 256, 0, stream>>>(csr, rowptr, dis, xlA, W2, b1, xlB);
    gather_pool_kernel <<<N_NODES / 4, 256, 0, stream>>>(csr, rowptr, dis, xlB, b2, Wc, sval);
    final_out_kernel<<<N_GRAPHS, 256, 0, stream>>>(sval, batch, bc, out);
}

// Round 13
// 463.319 us; speedup vs baseline: 1.0243x; 1.0243x over previous
//
#include <hip/hip_runtime.h>

#define N_NODES 100000
#define N_PAD   100352        // 392*256
#define N_EDGES 3200000
#define IN_DIM  128
#define HID     64
#define N_GRAPHS 256
#define NB      392           // buckets of 256 dest nodes each
#define NBLK    256           // hist/scatter blocks
#define EPB     (N_EDGES / NBLK)   // 12500

typedef unsigned short ushort_t;
typedef unsigned int   uint_t;

// bf16 helpers: storage-only compression of the gathered operand
__device__ __forceinline__ ushort_t f2bf(float v) {          // round-to-nearest-even
    uint_t b = __float_as_uint(v);
    b += 0x7fffu + ((b >> 16) & 1u);
    return (ushort_t)(b >> 16);
}
__device__ __forceinline__ void bf2f2(uint_t u, float& lo, float& hi) {
    lo = __uint_as_float(u << 16);
    hi = __uint_as_float(u & 0xffff0000u);
}
// 16B load -> 8 floats
__device__ __forceinline__ void ld_bf16x8(const ushort_t* p, float4& a, float4& b) {
    uint4 u = *(const uint4*)p;
    bf2f2(u.x, a.x, a.y); bf2f2(u.y, a.z, a.w);
    bf2f2(u.z, b.x, b.y); bf2f2(u.w, b.z, b.w);
}

// ---------- phase 1: per-block bucket histogram (dual LDS tables, no global atomics) ----
__global__ __launch_bounds__(256) void bhist_kernel(const int* __restrict__ col,
                                                    int* __restrict__ H) {
    __shared__ int h[2][NB];
    for (int i = threadIdx.x; i < NB; i += 256) { h[0][i] = 0; h[1][i] = 0; }
    __syncthreads();
    const int4* col4 = (const int4*)col;
    int base4 = blockIdx.x * (EPB / 4);
    int sel = threadIdx.x & 1;
    for (int j = threadIdx.x; j < EPB / 4; j += 256) {
        int4 c = col4[base4 + j];
        atomicAdd(&h[sel][c.x >> 8], 1);
        atomicAdd(&h[sel][c.y >> 8], 1);
        atomicAdd(&h[sel][c.z >> 8], 1);
        atomicAdd(&h[sel][c.w >> 8], 1);
    }
    __syncthreads();
    for (int i = threadIdx.x; i < NB; i += 256) H[i * NBLK + blockIdx.x] = h[0][i] + h[1][i];
}

// ---------- phase 2: exclusive scan of H (NB*NBLK, bucket-major) ----------
__global__ __launch_bounds__(256) void scan1_kernel(int* H, int* __restrict__ bsum) {
    __shared__ int s[256];
    int i = blockIdx.x * 256 + threadIdx.x;   // blockIdx.x == bucket (NBLK==256)
    int v = H[i];
    s[threadIdx.x] = v;
    __syncthreads();
    #pragma unroll
    for (int off = 1; off < 256; off <<= 1) {
        int t = (threadIdx.x >= off) ? s[threadIdx.x - off] : 0;
        __syncthreads();
        s[threadIdx.x] += t;
        __syncthreads();
    }
    H[i] = s[threadIdx.x] - v;                           // exclusive within bucket
    if (threadIdx.x == 255) bsum[blockIdx.x] = s[255];   // bucket total
}

// ---------- phase 3: LDS-staged scatter — bucket-sort the block's 12500 records in LDS,
// then write each bucket run as a coalesced contiguous burst (kills write amplification).
// rec = (row | local<<17, ew); local = col & 255 (8 bits), row < 2^17
__global__ __launch_bounds__(256) void bscatter_kernel(const int* __restrict__ row,
                                                       const int* __restrict__ col,
                                                       const float* __restrict__ ew,
                                                       const int* __restrict__ H,
                                                       const int* __restrict__ bsum,
                                                       int* __restrict__ boff,
                                                       int2* __restrict__ recs) {
    __shared__ int2 lrec[EPB];        // 100 KB: the block's records, bucket-sorted
    __shared__ int  lofs[NB];         // local exclusive offsets (LDS placement)
    __shared__ int  hcnt[NB];         // this block's count per bucket
    __shared__ int  gofs[NB];         // global dest offset per bucket
    __shared__ int  cur[NB];
    __shared__ int  s[256];
    __shared__ int  carry;
    int tid = threadIdx.x, blk = blockIdx.x;
    if (tid == 0) carry = 0;
    __syncthreads();
    // pass 1 over buckets: tboff (scan of bsum) + local count + gofs
    for (int c = 0; c < 2; ++c) {                 // 2*256 >= NB
        int i = c * 256 + tid;
        int v = (i < NB) ? bsum[i] : 0;
        s[tid] = v;
        __syncthreads();
        #pragma unroll
        for (int off = 1; off < 256; off <<= 1) {
            int t = (tid >= off) ? s[tid - off] : 0;
            __syncthreads();
            s[tid] += t;
            __syncthreads();
        }
        if (i < NB) {
            int tb = s[tid] - v + carry;          // bucket start in recs
            int ex = H[i * NBLK + blk];           // exclusive within bucket
            gofs[i] = tb + ex;
            hcnt[i] = ((blk < NBLK - 1) ? H[i * NBLK + blk + 1] : v) - ex;
            if (blk == 0) boff[i] = tb;           // publish for later kernels
        }
        __syncthreads();
        if (tid == 0) carry += s[255];
        __syncthreads();
    }
    // local exclusive scan of hcnt -> lofs
    if (tid == 0) carry = 0;
    __syncthreads();
    for (int c = 0; c < 2; ++c) {
        int i = c * 256 + tid;
        int v = (i < NB) ? hcnt[i] : 0;
        s[tid] = v;
        __syncthreads();
        #pragma unroll
        for (int off = 1; off < 256; off <<= 1) {
            int t = (tid >= off) ? s[tid - off] : 0;
            __syncthreads();
            s[tid] += t;
            __syncthreads();
        }
        if (i < NB) { int l = s[tid] - v + carry; lofs[i] = l; cur[i] = l; }
        __syncthreads();
        if (tid == 0) carry += s[255];
        __syncthreads();
    }
    // place records into LDS, bucket-sorted
    const int4*   row4 = (const int4*)row;
    const int4*   col4 = (const int4*)col;
    const float4* ew4  = (const float4*)ew;
    int base4 = blk * (EPB / 4);
    for (int j = tid; j < EPB / 4; j += 256) {
        int4   r4 = row4[base4 + j];
        int4   c4 = col4[base4 + j];
        float4 w4 = ew4[base4 + j];
        int p0 = atomicAdd(&cur[c4.x >> 8], 1);
        lrec[p0] = make_int2(r4.x | ((c4.x & 255) << 17), __float_as_int(w4.x));
        int p1 = atomicAdd(&cur[c4.y >> 8], 1);
        lrec[p1] = make_int2(r4.y | ((c4.y & 255) << 17), __float_as_int(w4.y));
        int p2 = atomicAdd(&cur[c4.z >> 8], 1);
        lrec[p2] = make_int2(r4.z | ((c4.z & 255) << 17), __float_as_int(w4.z));
        int p3 = atomicAdd(&cur[c4.w >> 8], 1);
        lrec[p3] = make_int2(r4.w | ((c4.w & 255) << 17), __float_as_int(w4.w));
    }
    __syncthreads();
    // write out each bucket's run contiguously (wave per bucket, round-robin)
    int wv = tid >> 6, lane = tid & 63;
    for (int i = wv; i < NB; i += 4) {
        int cnt = hcnt[i], lo = lofs[i], go = gofs[i];
        for (int k = lane; k < cnt; k += 64)
            recs[go + k] = lrec[lo + k];
    }
}

// ---------- phase 3.5: ONE recs pass -> deg + cnt; writes dis AND rowptr ----------
__global__ __launch_bounds__(256) void degcnt_kernel(const int2* __restrict__ recs,
                                                     const int* __restrict__ boff,
                                                     float* __restrict__ dis,
                                                     int* __restrict__ rowptr) {
    __shared__ int   cnt[256];
    __shared__ float degf[256];
    __shared__ int   sscan[256];
    int b = blockIdx.x, tid = threadIdx.x;
    cnt[tid] = 0; degf[tid] = 0.f;
    __syncthreads();
    int s = boff[b], e = (b + 1 < NB) ? boff[b + 1] : N_EDGES;
    for (int j = s + tid; j < e; j += 256) {
        int2 r = recs[j];
        int cl = (r.x >> 17) & 255;
        atomicAdd(&cnt[cl], 1);
        atomicAdd(&degf[cl], __int_as_float(r.y));
    }
    __syncthreads();
    int c = cnt[tid];
    sscan[tid] = c;
    __syncthreads();
    #pragma unroll
    for (int off = 1; off < 256; off <<= 1) {
        int t = (tid >= off) ? sscan[tid - off] : 0;
        __syncthreads();
        sscan[tid] += t;
        __syncthreads();
    }
    rowptr[b * 256 + tid] = s + sscan[tid] - c;   // exclusive; pad nodes get == e
    dis[b * 256 + tid] = 1.0f / sqrtf(fmaxf(1.0f + degf[tid], 1e-30f));
}

// ---------- phase 4: scatter-only CSR write; cursors seeded from rowptr ----------
// csr[pos] = (row, dis[row] * ew * dis[col])
__global__ __launch_bounds__(256) void csrw_kernel(const int2* __restrict__ recs,
                                                   const int* __restrict__ boff,
                                                   const float* __restrict__ dis,
                                                   const int* __restrict__ rowptr,
                                                   float2* __restrict__ csr) {
    __shared__ int   cur[256];
    __shared__ float sdis[256];
    int b = blockIdx.x, tid = threadIdx.x;
    cur[tid]  = rowptr[b * 256 + tid];
    sdis[tid] = dis[b * 256 + tid];
    __syncthreads();
    int s = boff[b], e = (b + 1 < NB) ? boff[b + 1] : N_EDGES;
    for (int j = s + tid; j < e; j += 256) {
        int2 r = recs[j];
        int cl = (r.x >> 17) & 255;
        int rr = r.x & 0x1FFFF;
        int pos = atomicAdd(&cur[cl], 1);
        csr[pos] = make_float2(__int_as_float(rr),
                               dis[rr] * __int_as_float(r.y) * sdis[cl]);
    }
}

// ---------- layer 1 GEMM: xl = x @ W1 (bf16 output), 8 rows/block ----------
__global__ __launch_bounds__(256) void gemm1_kernel(const float* __restrict__ x,
                                                    const float* __restrict__ W1,
                                                    ushort_t* __restrict__ xl) {
    __shared__ float sW[IN_DIM * HID];   // 32 KB
    __shared__ float sx[8][IN_DIM];      // 4 KB
    int tid = threadIdx.x;
    const float4* W4  = (const float4*)W1;
    float4*       sW4 = (float4*)sW;
    #pragma unroll
    for (int i = 0; i < 8; ++i) sW4[tid + 256 * i] = W4[tid + 256 * i];
    int r0 = blockIdx.x * 8;             // grid 12500 exact
    const float4* x4  = (const float4*)(x + (size_t)r0 * IN_DIM);
    float4*       sx4 = (float4*)&sx[0][0];
    sx4[tid] = x4[tid];                  // 256 float4 = 8 rows x 128
    __syncthreads();
    int c = tid & 63;
    #pragma unroll
    for (int rep = 0; rep < 2; ++rep) {
        int lr = (tid >> 6) * 2 + rep;   // 0..7
        float acc = 0.f;
        #pragma unroll 8
        for (int k = 0; k < IN_DIM; ++k) acc += sx[lr][k] * sW[k * HID + c];
        xl[(size_t)(r0 + lr) * HID + c] = f2bf(acc);
    }
}

// ---------- gather core: 8-lane groups, 16B loads, 4 edges in flight/group ----------
// lanes 0..7 hold the final 64-channel row (8 channels each) after reduction
__device__ __forceinline__ void gather_row(const float2* __restrict__ csr,
                                           const ushort_t* __restrict__ xl,
                                           int base, int end, int n, float d2,
                                           int g, int c0,
                                           float4& a0, float4& a1) {
    a0 = make_float4(0.f, 0.f, 0.f, 0.f);
    a1 = make_float4(0.f, 0.f, 0.f, 0.f);
    if (g == 0) {
        float4 s0, s1;
        ld_bf16x8(xl + (size_t)n * HID + c0, s0, s1);
        a0.x = s0.x * d2; a0.y = s0.y * d2; a0.z = s0.z * d2; a0.w = s0.w * d2;
        a1.x = s1.x * d2; a1.y = s1.y * d2; a1.z = s1.z * d2; a1.w = s1.w * d2;
    }
    int j = base + g;
    for (; j + 24 < end; j += 32) {                      // 4 edges in flight
        float2 e0 = csr[j];
        float2 e1 = csr[j + 8];
        float2 e2 = csr[j + 16];
        float2 e3 = csr[j + 24];
        int r0_ = __float_as_int(e0.x), r1_ = __float_as_int(e1.x);
        int r2_ = __float_as_int(e2.x), r3_ = __float_as_int(e3.x);
        float4 xa0, xa1, xb0, xb1, xc0, xc1, xd0, xd1;
        ld_bf16x8(xl + (size_t)r0_ * HID + c0, xa0, xa1);
        ld_bf16x8(xl + (size_t)r1_ * HID + c0, xb0, xb1);
        ld_bf16x8(xl + (size_t)r2_ * HID + c0, xc0, xc1);
        ld_bf16x8(xl + (size_t)r3_ * HID + c0, xd0, xd1);
        a0.x += xa0.x * e0.y + xb0.x * e1.y + xc0.x * e2.y + xd0.x * e3.y;
        a0.y += xa0.y * e0.y + xb0.y * e1.y + xc0.y * e2.y + xd0.y * e3.y;
        a0.z += xa0.z * e0.y + xb0.z * e1.y + xc0.z * e2.y + xd0.z * e3.y;
        a0.w += xa0.w * e0.y + xb0.w * e1.y + xc0.w * e2.y + xd0.w * e3.y;
        a1.x += xa1.x * e0.y + xb1.x * e1.y + xc1.x * e2.y + xd1.x * e3.y;
        a1.y += xa1.y * e0.y + xb1.y * e1.y + xc1.y * e2.y + xd1.y * e3.y;
        a1.z += xa1.z * e0.y + xb1.z * e1.y + xc1.z * e2.y + xd1.z * e3.y;
        a1.w += xa1.w * e0.y + xb1.w * e1.y + xc1.w * e2.y + xd1.w * e3.y;
    }
    for (; j < end; j += 8) {
        float2 e0 = csr[j];
        int ra = __float_as_int(e0.x);
        float w0 = e0.y;
        float4 xa0, xa1;
        ld_bf16x8(xl + (size_t)ra * HID + c0, xa0, xa1);
        a0.x += xa0.x * w0; a0.y += xa0.y * w0; a0.z += xa0.z * w0; a0.w += xa0.w * w0;
        a1.x += xa1.x * w0; a1.y += xa1.y * w0; a1.z += xa1.z * w0; a1.w += xa1.w * w0;
    }
    #pragma unroll
    for (int o = 32; o >= 8; o >>= 1) {
        a0.x += __shfl_down(a0.x, o, 64); a0.y += __shfl_down(a0.y, o, 64);
        a0.z += __shfl_down(a0.z, o, 64); a0.w += __shfl_down(a0.w, o, 64);
        a1.x += __shfl_down(a1.x, o, 64); a1.y += __shfl_down(a1.y, o, 64);
        a1.z += __shfl_down(a1.z, o, 64); a1.w += __shfl_down(a1.w, o, 64);
    }
}

// ---------- fused gather1 + gemm2: xl2 = relu(gather(xl1) + b1) @ W2 (bf16 out) ----------
__global__ __launch_bounds__(256) void gather_gemm2_kernel(
        const float2* __restrict__ csr, const int* __restrict__ rowptr,
        const float* __restrict__ dis, const ushort_t* __restrict__ xl,
        const float* __restrict__ W2, const float* __restrict__ b1,
        ushort_t* __restrict__ xl2) {
    __shared__ float sW[HID * HID];   // 16 KB
    __shared__ float sh[4][HID];
    __shared__ float sb1[HID];
    int tid = threadIdx.x;
    const float4* W4  = (const float4*)W2;
    float4*       sW4 = (float4*)sW;
    #pragma unroll
    for (int i = 0; i < 4; ++i) sW4[tid + 256 * i] = W4[tid + 256 * i];
    if (tid < HID) sb1[tid] = b1[tid];

    int r0   = blockIdx.x * 4;
    int wv   = tid >> 6;
    int n    = r0 + wv;
    int lane = tid & 63;
    int g    = lane >> 3;
    int c0   = (lane & 7) << 3;
    int base = rowptr[n], end = rowptr[n + 1];
    float d  = dis[n];
    float4 a0, a1;
    gather_row(csr, xl, base, end, n, d * d, g, c0, a0, a1);
    if (lane < 8) {
        *(float4*)(&sh[wv][c0])     = a0;
        *(float4*)(&sh[wv][c0 + 4]) = a1;
    }
    __syncthreads();                                    // sW, sb1, sh all visible
    int lr = wv, cc = lane;
    float hv = fmaxf(sh[lr][cc] + sb1[cc], 0.f);        // relu(agg1 + b1)
    __syncthreads();
    sh[lr][cc] = hv;
    __syncthreads();
    float acc2 = 0.f;
    #pragma unroll 8
    for (int k = 0; k < HID; ++k) acc2 += sh[lr][k] * sW[k * HID + cc];
    xl2[(size_t)(r0 + lr) * HID + cc] = f2bf(acc2);
}

// ---------- fused gather2 + pool partial: sval[n] = relu(agg2[n]+b2) . Wc ----------
// coalesced scalar store per node; NO atomics (256-slot atomic target serializes at L2)
__global__ __launch_bounds__(256) void gather_pool_kernel(
        const float2* __restrict__ csr, const int* __restrict__ rowptr,
        const float* __restrict__ dis, const ushort_t* __restrict__ xl,
        const float* __restrict__ b2, const float* __restrict__ Wc,
        float* __restrict__ sval) {
    int tid  = threadIdx.x;
    int n    = (blockIdx.x * 256 + tid) >> 6;           // grid 25000 exact
    int lane = tid & 63;
    int g    = lane >> 3;
    int c0   = (lane & 7) << 3;
    int base = rowptr[n], end = rowptr[n + 1];
    float d  = dis[n];
    float4 a0, a1;
    gather_row(csr, xl, base, end, n, d * d, g, c0, a0, a1);
    if (lane < 8) {
        float4 bb0 = *(const float4*)(b2 + c0);
        float4 bb1 = *(const float4*)(b2 + c0 + 4);
        float4 wc0 = *(const float4*)(Wc + c0);
        float4 wc1 = *(const float4*)(Wc + c0 + 4);
        float s = fmaxf(a0.x + bb0.x, 0.f) * wc0.x + fmaxf(a0.y + bb0.y, 0.f) * wc0.y
                + fmaxf(a0.z + bb0.z, 0.f) * wc0.z + fmaxf(a0.w + bb0.w, 0.f) * wc0.w
                + fmaxf(a1.x + bb1.x, 0.f) * wc1.x + fmaxf(a1.y + bb1.y, 0.f) * wc1.y
                + fmaxf(a1.z + bb1.z, 0.f) * wc1.z + fmaxf(a1.w + bb1.w, 0.f) * wc1.w;
        s += __shfl_down(s, 4, 64);
        s += __shfl_down(s, 2, 64);
        s += __shfl_down(s, 1, 64);
        if (lane == 0) sval[n] = s;
    }
}

// ---------- final: out[g] = mean(sval over graph range) + bc ----------
__global__ __launch_bounds__(256) void final_out_kernel(const float* __restrict__ sval,
                                                        const int* __restrict__ batch,
                                                        const float* __restrict__ bc,
                                                        float* __restrict__ out) {
    __shared__ float s[256];
    int g = blockIdx.x;   // grid N_GRAPHS
    int lo = 0, hi = N_NODES;
    while (lo < hi) { int m = (lo + hi) >> 1; if (batch[m] < g) lo = m + 1; else hi = m; }
    int start = lo;
    hi = N_NODES;
    while (lo < hi) { int m = (lo + hi) >> 1; if (batch[m] < g + 1) lo = m + 1; else hi = m; }
    int end = lo;
    float acc = 0.f;
    for (int i = start + threadIdx.x; i < end; i += 256) acc += sval[i];
    s[threadIdx.x] = acc;
    __syncthreads();
    #pragma unroll
    for (int off = 128; off > 0; off >>= 1) {
        if (threadIdx.x < off) s[threadIdx.x] += s[threadIdx.x + off];
        __syncthreads();
    }
    if (threadIdx.x == 0)
        out[g] = s[0] / fmaxf((float)(end - start), 1.0f) + bc[0];
}

extern "C" void kernel_launch(void* const* d_in, const int* in_sizes, int n_in,
                              void* d_out, int out_size, void* d_ws, size_t ws_size,
                              hipStream_t stream) {
    const float* x     = (const float*)d_in[0];
    const int*   ei    = (const int*)  d_in[1];
    const float* ew    = (const float*)d_in[2];
    const int*   batch = (const int*)  d_in[3];
    const float* W1    = (const float*)d_in[4];
    const float* b1    = (const float*)d_in[5];
    const float* W2    = (const float*)d_in[6];
    const float* b2    = (const float*)d_in[7];
    const float* Wc    = (const float*)d_in[8];
    const float* bc    = (const float*)d_in[9];
    float* out = (float*)d_out;

    const int* row = ei;
    const int* col = ei + N_EDGES;

    // workspace (~78 MB): recs | xlA | xlB | csr | rowptr | dis | bsum | boff | sval
    // H aliases csr (dead before csrw writes csr).
    int2*     recs   = (int2*)d_ws;                              // E int2 = 25.6 MB
    ushort_t* xlA    = (ushort_t*)(recs + N_EDGES);              // N*HID bf16
    ushort_t* xlB    = xlA + (size_t)N_NODES * HID;              // N*HID bf16
    float2*   csr    = (float2*)(xlB + (size_t)N_NODES * HID);   // E float2
    int*      rowptr = (int*)(csr + N_EDGES);                    // N_PAD
    float*    dis    = (float*)(rowptr + N_PAD);                 // N_PAD
    int*      bsum   = (int*)(dis + N_PAD);                      // 512
    int*      boff   = bsum + 512;                               // 512
    float*    sval   = (float*)(boff + 512);                     // N_PAD
    int*      H      = (int*)csr;                                // NB*NBLK ints = 401 KB

    bhist_kernel    <<<NBLK, 256, 0, stream>>>(col, H);
    scan1_kernel    <<<NB,   256, 0, stream>>>(H, bsum);
    bscatter_kernel <<<NBLK, 256, 0, stream>>>(row, col, ew, H, bsum, boff, recs);
    degcnt_kernel   <<<NB,   256, 0, stream>>>(recs, boff, dis, rowptr);
    csrw_kernel     <<<NB,   256, 0, stream>>>(recs, boff, dis, rowptr, csr);
    gemm1_kernel    <<<N_NODES / 8, 256, 0, stream>>>(x, W1, xlA);
    gather_gemm2_kernel<<<N_NODES / 4, 256, 0, stream>>>(csr, rowptr, dis, xlA, W2, b1, xlB);
    gather_pool_kernel <<<N_NODES / 4, 256, 0, stream>>>(csr, rowptr, dis, xlB, b2, Wc, sval);
    final_out_kernel<<<N_GRAPHS, 256, 0, stream>>>(sval, batch, bc, out);
}

// Round 14
// 454.286 us; speedup vs baseline: 1.0446x; 1.0199x over previous
//
#include <hip/hip_runtime.h>

#define N_NODES 100000
#define N_PAD   100352        // 392*256
#define N_EDGES 3200000
#define IN_DIM  128
#define HID     64
#define N_GRAPHS 256
#define NB      392           // buckets of 256 dest nodes each
#define NBLK    256           // hist/scatter blocks
#define EPB     (N_EDGES / NBLK)   // 12500
#define G1BLK   (N_NODES / 8)      // 12500 gemm1 blocks

typedef unsigned short ushort_t;
typedef unsigned int   uint_t;

// bf16 helpers: storage-only compression of the gathered operand
__device__ __forceinline__ ushort_t f2bf(float v) {          // round-to-nearest-even
    uint_t b = __float_as_uint(v);
    b += 0x7fffu + ((b >> 16) & 1u);
    return (ushort_t)(b >> 16);
}
__device__ __forceinline__ void bf2f2(uint_t u, float& lo, float& hi) {
    lo = __uint_as_float(u << 16);
    hi = __uint_as_float(u & 0xffff0000u);
}
// 16B load -> 8 floats
__device__ __forceinline__ void ld_bf16x8(const ushort_t* p, float4& a, float4& b) {
    uint4 u = *(const uint4*)p;
    bf2f2(u.x, a.x, a.y); bf2f2(u.y, a.z, a.w);
    bf2f2(u.z, b.x, b.y); bf2f2(u.w, b.z, b.w);
}

// ---------- phase 1 (fused): bucket histogram (blocks 0..NBLK-1) + gemm1 (rest) ----------
// gemm1 is independent of the build chain; co-residency hides its ~30 us.
__global__ __launch_bounds__(256) void bhist_gemm1_kernel(
        const int* __restrict__ col, int* __restrict__ H,
        const float* __restrict__ x, const float* __restrict__ W1,
        ushort_t* __restrict__ xl) {
    __shared__ int   h[2][NB];           // 3.1 KB
    __shared__ float sW[IN_DIM * HID];   // 32 KB
    __shared__ float sx[8][IN_DIM];      // 4 KB  (union 39 KB -> 4 blocks/CU)
    int tid = threadIdx.x;
    if (blockIdx.x < NBLK) {
        for (int i = tid; i < NB; i += 256) { h[0][i] = 0; h[1][i] = 0; }
        __syncthreads();
        const int4* col4 = (const int4*)col;
        int base4 = blockIdx.x * (EPB / 4);
        int sel = tid & 1;
        for (int j = tid; j < EPB / 4; j += 256) {
            int4 c = col4[base4 + j];
            atomicAdd(&h[sel][c.x >> 8], 1);
            atomicAdd(&h[sel][c.y >> 8], 1);
            atomicAdd(&h[sel][c.z >> 8], 1);
            atomicAdd(&h[sel][c.w >> 8], 1);
        }
        __syncthreads();
        for (int i = tid; i < NB; i += 256) H[i * NBLK + blockIdx.x] = h[0][i] + h[1][i];
    } else {
        int bid = blockIdx.x - NBLK;
        const float4* W4  = (const float4*)W1;
        float4*       sW4 = (float4*)sW;
        #pragma unroll
        for (int i = 0; i < 8; ++i) sW4[tid + 256 * i] = W4[tid + 256 * i];
        int r0 = bid * 8;
        const float4* x4  = (const float4*)(x + (size_t)r0 * IN_DIM);
        float4*       sx4 = (float4*)&sx[0][0];
        sx4[tid] = x4[tid];              // 256 float4 = 8 rows x 128
        __syncthreads();
        int c = tid & 63;
        #pragma unroll
        for (int rep = 0; rep < 2; ++rep) {
            int lr = (tid >> 6) * 2 + rep;   // 0..7
            float acc = 0.f;
            #pragma unroll 8
            for (int k = 0; k < IN_DIM; ++k) acc += sx[lr][k] * sW[k * HID + c];
            xl[(size_t)(r0 + lr) * HID + c] = f2bf(acc);
        }
    }
}

// ---------- phase 2: exclusive scan of H (NB*NBLK, bucket-major) ----------
__global__ __launch_bounds__(256) void scan1_kernel(int* H, int* __restrict__ bsum) {
    __shared__ int s[256];
    int i = blockIdx.x * 256 + threadIdx.x;   // blockIdx.x == bucket (NBLK==256)
    int v = H[i];
    s[threadIdx.x] = v;
    __syncthreads();
    #pragma unroll
    for (int off = 1; off < 256; off <<= 1) {
        int t = (threadIdx.x >= off) ? s[threadIdx.x - off] : 0;
        __syncthreads();
        s[threadIdx.x] += t;
        __syncthreads();
    }
    H[i] = s[threadIdx.x] - v;                           // exclusive within bucket
    if (threadIdx.x == 255) bsum[blockIdx.x] = s[255];   // bucket total
}

// ---------- phase 3: LDS-staged scatter — bucket-sort the block's 12500 records in LDS,
// then write each bucket run as a coalesced contiguous burst (kills write amplification).
// rec = (row | local<<17, ew); local = col & 255 (8 bits), row < 2^17
__global__ __launch_bounds__(256) void bscatter_kernel(const int* __restrict__ row,
                                                       const int* __restrict__ col,
                                                       const float* __restrict__ ew,
                                                       const int* __restrict__ H,
                                                       const int* __restrict__ bsum,
                                                       int* __restrict__ boff,
                                                       int2* __restrict__ recs) {
    __shared__ int2 lrec[EPB];        // 100 KB: the block's records, bucket-sorted
    __shared__ int  lofs[NB];         // local exclusive offsets (LDS placement)
    __shared__ int  hcnt[NB];         // this block's count per bucket
    __shared__ int  gofs[NB];         // global dest offset per bucket
    __shared__ int  cur[NB];
    __shared__ int  s[256];
    __shared__ int  carry;
    int tid = threadIdx.x, blk = blockIdx.x;
    if (tid == 0) carry = 0;
    __syncthreads();
    // pass 1 over buckets: tboff (scan of bsum) + local count + gofs
    for (int c = 0; c < 2; ++c) {                 // 2*256 >= NB
        int i = c * 256 + tid;
        int v = (i < NB) ? bsum[i] : 0;
        s[tid] = v;
        __syncthreads();
        #pragma unroll
        for (int off = 1; off < 256; off <<= 1) {
            int t = (tid >= off) ? s[tid - off] : 0;
            __syncthreads();
            s[tid] += t;
            __syncthreads();
        }
        if (i < NB) {
            int tb = s[tid] - v + carry;          // bucket start in recs
            int ex = H[i * NBLK + blk];           // exclusive within bucket
            gofs[i] = tb + ex;
            hcnt[i] = ((blk < NBLK - 1) ? H[i * NBLK + blk + 1] : v) - ex;
            if (blk == 0) boff[i] = tb;           // publish for later kernels
        }
        __syncthreads();
        if (tid == 0) carry += s[255];
        __syncthreads();
    }
    // local exclusive scan of hcnt -> lofs
    if (tid == 0) carry = 0;
    __syncthreads();
    for (int c = 0; c < 2; ++c) {
        int i = c * 256 + tid;
        int v = (i < NB) ? hcnt[i] : 0;
        s[tid] = v;
        __syncthreads();
        #pragma unroll
        for (int off = 1; off < 256; off <<= 1) {
            int t = (tid >= off) ? s[tid - off] : 0;
            __syncthreads();
            s[tid] += t;
            __syncthreads();
        }
        if (i < NB) { int l = s[tid] - v + carry; lofs[i] = l; cur[i] = l; }
        __syncthreads();
        if (tid == 0) carry += s[255];
        __syncthreads();
    }
    // place records into LDS, bucket-sorted
    const int4*   row4 = (const int4*)row;
    const int4*   col4 = (const int4*)col;
    const float4* ew4  = (const float4*)ew;
    int base4 = blk * (EPB / 4);
    for (int j = tid; j < EPB / 4; j += 256) {
        int4   r4 = row4[base4 + j];
        int4   c4 = col4[base4 + j];
        float4 w4 = ew4[base4 + j];
        int p0 = atomicAdd(&cur[c4.x >> 8], 1);
        lrec[p0] = make_int2(r4.x | ((c4.x & 255) << 17), __float_as_int(w4.x));
        int p1 = atomicAdd(&cur[c4.y >> 8], 1);
        lrec[p1] = make_int2(r4.y | ((c4.y & 255) << 17), __float_as_int(w4.y));
        int p2 = atomicAdd(&cur[c4.z >> 8], 1);
        lrec[p2] = make_int2(r4.z | ((c4.z & 255) << 17), __float_as_int(w4.z));
        int p3 = atomicAdd(&cur[c4.w >> 8], 1);
        lrec[p3] = make_int2(r4.w | ((c4.w & 255) << 17), __float_as_int(w4.w));
    }
    __syncthreads();
    // write out each bucket's run contiguously (wave per bucket, round-robin)
    int wv = tid >> 6, lane = tid & 63;
    for (int i = wv; i < NB; i += 4) {
        int cnt = hcnt[i], lo = lofs[i], go = gofs[i];
        for (int k = lane; k < cnt; k += 64)
            recs[go + k] = lrec[lo + k];
    }
}

// ---------- phase 3.5: ONE recs pass -> deg + cnt; writes dis AND rowptr ----------
__global__ __launch_bounds__(256) void degcnt_kernel(const int2* __restrict__ recs,
                                                     const int* __restrict__ boff,
                                                     float* __restrict__ dis,
                                                     int* __restrict__ rowptr) {
    __shared__ int   cnt[256];
    __shared__ float degf[256];
    __shared__ int   sscan[256];
    int b = blockIdx.x, tid = threadIdx.x;
    cnt[tid] = 0; degf[tid] = 0.f;
    __syncthreads();
    int s = boff[b], e = (b + 1 < NB) ? boff[b + 1] : N_EDGES;
    for (int j = s + tid; j < e; j += 256) {
        int2 r = recs[j];
        int cl = (r.x >> 17) & 255;
        atomicAdd(&cnt[cl], 1);
        atomicAdd(&degf[cl], __int_as_float(r.y));
    }
    __syncthreads();
    int c = cnt[tid];
    sscan[tid] = c;
    __syncthreads();
    #pragma unroll
    for (int off = 1; off < 256; off <<= 1) {
        int t = (tid >= off) ? sscan[tid - off] : 0;
        __syncthreads();
        sscan[tid] += t;
        __syncthreads();
    }
    rowptr[b * 256 + tid] = s + sscan[tid] - c;   // exclusive; pad nodes get == e
    dis[b * 256 + tid] = 1.0f / sqrtf(fmaxf(1.0f + degf[tid], 1e-30f));
}

// ---------- phase 4: scatter-only CSR write; cursors seeded from rowptr ----------
// csr[pos] = (row, dis[row] * ew * dis[col])
__global__ __launch_bounds__(256) void csrw_kernel(const int2* __restrict__ recs,
                                                   const int* __restrict__ boff,
                                                   const float* __restrict__ dis,
                                                   const int* __restrict__ rowptr,
                                                   float2* __restrict__ csr) {
    __shared__ int   cur[256];
    __shared__ float sdis[256];
    int b = blockIdx.x, tid = threadIdx.x;
    cur[tid]  = rowptr[b * 256 + tid];
    sdis[tid] = dis[b * 256 + tid];
    __syncthreads();
    int s = boff[b], e = (b + 1 < NB) ? boff[b + 1] : N_EDGES;
    for (int j = s + tid; j < e; j += 256) {
        int2 r = recs[j];
        int cl = (r.x >> 17) & 255;
        int rr = r.x & 0x1FFFF;
        int pos = atomicAdd(&cur[cl], 1);
        csr[pos] = make_float2(__int_as_float(rr),
                               dis[rr] * __int_as_float(r.y) * sdis[cl]);
    }
}

// ---------- gather core: 8-lane groups, 16B loads, 4 edges in flight/group ----------
// lanes 0..7 hold the final 64-channel row (8 channels each) after reduction
__device__ __forceinline__ void gather_row(const float2* __restrict__ csr,
                                           const ushort_t* __restrict__ xl,
                                           int base, int end, int n, float d2,
                                           int g, int c0,
                                           float4& a0, float4& a1) {
    a0 = make_float4(0.f, 0.f, 0.f, 0.f);
    a1 = make_float4(0.f, 0.f, 0.f, 0.f);
    if (g == 0) {
        float4 s0, s1;
        ld_bf16x8(xl + (size_t)n * HID + c0, s0, s1);
        a0.x = s0.x * d2; a0.y = s0.y * d2; a0.z = s0.z * d2; a0.w = s0.w * d2;
        a1.x = s1.x * d2; a1.y = s1.y * d2; a1.z = s1.z * d2; a1.w = s1.w * d2;
    }
    int j = base + g;
    for (; j + 24 < end; j += 32) {                      // 4 edges in flight
        float2 e0 = csr[j];
        float2 e1 = csr[j + 8];
        float2 e2 = csr[j + 16];
        float2 e3 = csr[j + 24];
        int r0_ = __float_as_int(e0.x), r1_ = __float_as_int(e1.x);
        int r2_ = __float_as_int(e2.x), r3_ = __float_as_int(e3.x);
        float4 xa0, xa1, xb0, xb1, xc0, xc1, xd0, xd1;
        ld_bf16x8(xl + (size_t)r0_ * HID + c0, xa0, xa1);
        ld_bf16x8(xl + (size_t)r1_ * HID + c0, xb0, xb1);
        ld_bf16x8(xl + (size_t)r2_ * HID + c0, xc0, xc1);
        ld_bf16x8(xl + (size_t)r3_ * HID + c0, xd0, xd1);
        a0.x += xa0.x * e0.y + xb0.x * e1.y + xc0.x * e2.y + xd0.x * e3.y;
        a0.y += xa0.y * e0.y + xb0.y * e1.y + xc0.y * e2.y + xd0.y * e3.y;
        a0.z += xa0.z * e0.y + xb0.z * e1.y + xc0.z * e2.y + xd0.z * e3.y;
        a0.w += xa0.w * e0.y + xb0.w * e1.y + xc0.w * e2.y + xd0.w * e3.y;
        a1.x += xa1.x * e0.y + xb1.x * e1.y + xc1.x * e2.y + xd1.x * e3.y;
        a1.y += xa1.y * e0.y + xb1.y * e1.y + xc1.y * e2.y + xd1.y * e3.y;
        a1.z += xa1.z * e0.y + xb1.z * e1.y + xc1.z * e2.y + xd1.z * e3.y;
        a1.w += xa1.w * e0.y + xb1.w * e1.y + xc1.w * e2.y + xd1.w * e3.y;
    }
    for (; j < end; j += 8) {
        float2 e0 = csr[j];
        int ra = __float_as_int(e0.x);
        float w0 = e0.y;
        float4 xa0, xa1;
        ld_bf16x8(xl + (size_t)ra * HID + c0, xa0, xa1);
        a0.x += xa0.x * w0; a0.y += xa0.y * w0; a0.z += xa0.z * w0; a0.w += xa0.w * w0;
        a1.x += xa1.x * w0; a1.y += xa1.y * w0; a1.z += xa1.z * w0; a1.w += xa1.w * w0;
    }
    #pragma unroll
    for (int o = 32; o >= 8; o >>= 1) {
        a0.x += __shfl_down(a0.x, o, 64); a0.y += __shfl_down(a0.y, o, 64);
        a0.z += __shfl_down(a0.z, o, 64); a0.w += __shfl_down(a0.w, o, 64);
        a1.x += __shfl_down(a1.x, o, 64); a1.y += __shfl_down(a1.y, o, 64);
        a1.z += __shfl_down(a1.z, o, 64); a1.w += __shfl_down(a1.w, o, 64);
    }
}

// ---------- fused gather1 + gemm2: xl2 = relu(gather(xl1) + b1) @ W2 (bf16 out) ----------
__global__ __launch_bounds__(256) void gather_gemm2_kernel(
        const float2* __restrict__ csr, const int* __restrict__ rowptr,
        const float* __restrict__ dis, const ushort_t* __restrict__ xl,
        const float* __restrict__ W2, const float* __restrict__ b1,
        ushort_t* __restrict__ xl2) {
    __shared__ float sW[HID * HID];   // 16 KB
    __shared__ float sh[4][HID];
    __shared__ float sb1[HID];
    int tid = threadIdx.x;
    const float4* W4  = (const float4*)W2;
    float4*       sW4 = (float4*)sW;
    #pragma unroll
    for (int i = 0; i < 4; ++i) sW4[tid + 256 * i] = W4[tid + 256 * i];
    if (tid < HID) sb1[tid] = b1[tid];

    int r0   = blockIdx.x * 4;
    int wv   = tid >> 6;
    int n    = r0 + wv;
    int lane = tid & 63;
    int g    = lane >> 3;
    int c0   = (lane & 7) << 3;
    int base = rowptr[n], end = rowptr[n + 1];
    float d  = dis[n];
    float4 a0, a1;
    gather_row(csr, xl, base, end, n, d * d, g, c0, a0, a1);
    if (lane < 8) {
        *(float4*)(&sh[wv][c0])     = a0;
        *(float4*)(&sh[wv][c0 + 4]) = a1;
    }
    __syncthreads();                                    // sW, sb1, sh all visible
    int lr = wv, cc = lane;
    float hv = fmaxf(sh[lr][cc] + sb1[cc], 0.f);        // relu(agg1 + b1)
    __syncthreads();
    sh[lr][cc] = hv;
    __syncthreads();
    float acc2 = 0.f;
    #pragma unroll 8
    for (int k = 0; k < HID; ++k) acc2 += sh[lr][k] * sW[k * HID + cc];
    xl2[(size_t)(r0 + lr) * HID + cc] = f2bf(acc2);
}

// ---------- fused gather2 + pool partial: sval[n] = relu(agg2[n]+b2) . Wc ----------
// coalesced scalar store per node; NO atomics (256-slot atomic target serializes at L2)
__global__ __launch_bounds__(256) void gather_pool_kernel(
        const float2* __restrict__ csr, const int* __restrict__ rowptr,
        const float* __restrict__ dis, const ushort_t* __restrict__ xl,
        const float* __restrict__ b2, const float* __restrict__ Wc,
        float* __restrict__ sval) {
    int tid  = threadIdx.x;
    int n    = (blockIdx.x * 256 + tid) >> 6;           // grid 25000 exact
    int lane = tid & 63;
    int g    = lane >> 3;
    int c0   = (lane & 7) << 3;
    int base = rowptr[n], end = rowptr[n + 1];
    float d  = dis[n];
    float4 a0, a1;
    gather_row(csr, xl, base, end, n, d * d, g, c0, a0, a1);
    if (lane < 8) {
        float4 bb0 = *(const float4*)(b2 + c0);
        float4 bb1 = *(const float4*)(b2 + c0 + 4);
        float4 wc0 = *(const float4*)(Wc + c0);
        float4 wc1 = *(const float4*)(Wc + c0 + 4);
        float s = fmaxf(a0.x + bb0.x, 0.f) * wc0.x + fmaxf(a0.y + bb0.y, 0.f) * wc0.y
                + fmaxf(a0.z + bb0.z, 0.f) * wc0.z + fmaxf(a0.w + bb0.w, 0.f) * wc0.w
                + fmaxf(a1.x + bb1.x, 0.f) * wc1.x + fmaxf(a1.y + bb1.y, 0.f) * wc1.y
                + fmaxf(a1.z + bb1.z, 0.f) * wc1.z + fmaxf(a1.w + bb1.w, 0.f) * wc1.w;
        s += __shfl_down(s, 4, 64);
        s += __shfl_down(s, 2, 64);
        s += __shfl_down(s, 1, 64);
        if (lane == 0) sval[n] = s;
    }
}

// ---------- final: out[g] = mean(sval over graph range) + bc ----------
__global__ __launch_bounds__(256) void final_out_kernel(const float* __restrict__ sval,
                                                        const int* __restrict__ batch,
                                                        const float* __restrict__ bc,
                                                        float* __restrict__ out) {
    __shared__ float s[256];
    int g = blockIdx.x;   // grid N_GRAPHS
    int lo = 0, hi = N_NODES;
    while (lo < hi) { int m = (lo + hi) >> 1; if (batch[m] < g) lo = m + 1; else hi = m; }
    int start = lo;
    hi = N_NODES;
    while (lo < hi) { int m = (lo + hi) >> 1; if (batch[m] < g + 1) lo = m + 1; else hi = m; }
    int end = lo;
    float acc = 0.f;
    for (int i = start + threadIdx.x; i < end; i += 256) acc += sval[i];
    s[threadIdx.x] = acc;
    __syncthreads();
    #pragma unroll
    for (int off = 128; off > 0; off >>= 1) {
        if (threadIdx.x < off) s[threadIdx.x] += s[threadIdx.x + off];
        __syncthreads();
    }
    if (threadIdx.x == 0)
        out[g] = s[0] / fmaxf((float)(end - start), 1.0f) + bc[0];
}

extern "C" void kernel_launch(void* const* d_in, const int* in_sizes, int n_in,
                              void* d_out, int out_size, void* d_ws, size_t ws_size,
                              hipStream_t stream) {
    const float* x     = (const float*)d_in[0];
    const int*   ei    = (const int*)  d_in[1];
    const float* ew    = (const float*)d_in[2];
    const int*   batch = (const int*)  d_in[3];
    const float* W1    = (const float*)d_in[4];
    const float* b1    = (const float*)d_in[5];
    const float* W2    = (const float*)d_in[6];
    const float* b2    = (const float*)d_in[7];
    const float* Wc    = (const float*)d_in[8];
    const float* bc    = (const float*)d_in[9];
    float* out = (float*)d_out;

    const int* row = ei;
    const int* col = ei + N_EDGES;

    // workspace (~78 MB): recs | xlA | xlB | csr | rowptr | dis | bsum | boff | sval
    // H aliases csr (dead before csrw writes csr).
    int2*     recs   = (int2*)d_ws;                              // E int2 = 25.6 MB
    ushort_t* xlA    = (ushort_t*)(recs + N_EDGES);              // N*HID bf16
    ushort_t* xlB    = xlA + (size_t)N_NODES * HID;              // N*HID bf16
    float2*   csr    = (float2*)(xlB + (size_t)N_NODES * HID);   // E float2
    int*      rowptr = (int*)(csr + N_EDGES);                    // N_PAD
    float*    dis    = (float*)(rowptr + N_PAD);                 // N_PAD
    int*      bsum   = (int*)(dis + N_PAD);                      // 512
    int*      boff   = bsum + 512;                               // 512
    float*    sval   = (float*)(boff + 512);                     // N_PAD
    int*      H      = (int*)csr;                                // NB*NBLK ints = 401 KB

    bhist_gemm1_kernel<<<NBLK + G1BLK, 256, 0, stream>>>(col, H, x, W1, xlA);
    scan1_kernel    <<<NB,   256, 0, stream>>>(H, bsum);
    bscatter_kernel <<<NBLK, 256, 0, stream>>>(row, col, ew, H, bsum, boff, recs);
    degcnt_kernel   <<<NB,   256, 0, stream>>>(recs, boff, dis, rowptr);
    csrw_kernel     <<<NB,   256, 0, stream>>>(recs, boff, dis, rowptr, csr);
    gather_gemm2_kernel<<<N_NODES / 4, 256, 0, stream>>>(csr, rowptr, dis, xlA, W2, b1, xlB);
    gather_pool_kernel <<<N_NODES / 4, 256, 0, stream>>>(csr, rowptr, dis, xlB, b2, Wc, sval);
    final_out_kernel<<<N_GRAPHS, 256, 0, stream>>>(sval, batch, bc, out);
}

// Round 15
// 446.388 us; speedup vs baseline: 1.0631x; 1.0177x over previous
//
#include <hip/hip_runtime.h>

#define N_NODES 100000
#define N_PAD   100352        // 392*256
#define N_EDGES 3200000
#define IN_DIM  128
#define HID     64
#define N_GRAPHS 256
#define NB      392           // buckets of 256 dest nodes each
#define NBLK    256           // hist/scatter blocks
#define EPB     (N_EDGES / NBLK)   // 12500
#define G1BLK   (N_NODES / 8)      // 12500 gemm1 blocks

typedef unsigned short ushort_t;
typedef unsigned int   uint_t;

// bf16 helpers: storage-only compression of the gathered operand
__device__ __forceinline__ ushort_t f2bf(float v) {          // round-to-nearest-even
    uint_t b = __float_as_uint(v);
    b += 0x7fffu + ((b >> 16) & 1u);
    return (ushort_t)(b >> 16);
}
__device__ __forceinline__ void bf2f2(uint_t u, float& lo, float& hi) {
    lo = __uint_as_float(u << 16);
    hi = __uint_as_float(u & 0xffff0000u);
}
// 16B load -> 8 floats
__device__ __forceinline__ void ld_bf16x8(const ushort_t* p, float4& a, float4& b) {
    uint4 u = *(const uint4*)p;
    bf2f2(u.x, a.x, a.y); bf2f2(u.y, a.z, a.w);
    bf2f2(u.z, b.x, b.y); bf2f2(u.w, b.z, b.w);
}

// ---------- phase 1 (fused): bucket histogram (blocks 0..NBLK-1) + gemm1 (rest) ----------
__global__ __launch_bounds__(256) void bhist_gemm1_kernel(
        const int* __restrict__ col, int* __restrict__ H,
        const float* __restrict__ x, const float* __restrict__ W1,
        ushort_t* __restrict__ xl) {
    __shared__ int   h[2][NB];           // 3.1 KB
    __shared__ float sW[IN_DIM * HID];   // 32 KB
    __shared__ float sx[8][IN_DIM];      // 4 KB  (union 39 KB -> 4 blocks/CU)
    int tid = threadIdx.x;
    if (blockIdx.x < NBLK) {
        for (int i = tid; i < NB; i += 256) { h[0][i] = 0; h[1][i] = 0; }
        __syncthreads();
        const int4* col4 = (const int4*)col;
        int base4 = blockIdx.x * (EPB / 4);
        int sel = tid & 1;
        for (int j = tid; j < EPB / 4; j += 256) {
            int4 c = col4[base4 + j];
            atomicAdd(&h[sel][c.x >> 8], 1);
            atomicAdd(&h[sel][c.y >> 8], 1);
            atomicAdd(&h[sel][c.z >> 8], 1);
            atomicAdd(&h[sel][c.w >> 8], 1);
        }
        __syncthreads();
        for (int i = tid; i < NB; i += 256) H[i * NBLK + blockIdx.x] = h[0][i] + h[1][i];
    } else {
        int bid = blockIdx.x - NBLK;
        const float4* W4  = (const float4*)W1;
        float4*       sW4 = (float4*)sW;
        #pragma unroll
        for (int i = 0; i < 8; ++i) sW4[tid + 256 * i] = W4[tid + 256 * i];
        int r0 = bid * 8;
        const float4* x4  = (const float4*)(x + (size_t)r0 * IN_DIM);
        float4*       sx4 = (float4*)&sx[0][0];
        sx4[tid] = x4[tid];              // 256 float4 = 8 rows x 128
        __syncthreads();
        int c = tid & 63;
        #pragma unroll
        for (int rep = 0; rep < 2; ++rep) {
            int lr = (tid >> 6) * 2 + rep;   // 0..7
            float acc = 0.f;
            #pragma unroll 8
            for (int k = 0; k < IN_DIM; ++k) acc += sx[lr][k] * sW[k * HID + c];
            xl[(size_t)(r0 + lr) * HID + c] = f2bf(acc);
        }
    }
}

// ---------- phase 2: exclusive scan of H (NB*NBLK, bucket-major) ----------
__global__ __launch_bounds__(256) void scan1_kernel(int* H, int* __restrict__ bsum) {
    __shared__ int s[256];
    int i = blockIdx.x * 256 + threadIdx.x;   // blockIdx.x == bucket (NBLK==256)
    int v = H[i];
    s[threadIdx.x] = v;
    __syncthreads();
    #pragma unroll
    for (int off = 1; off < 256; off <<= 1) {
        int t = (threadIdx.x >= off) ? s[threadIdx.x - off] : 0;
        __syncthreads();
        s[threadIdx.x] += t;
        __syncthreads();
    }
    H[i] = s[threadIdx.x] - v;                           // exclusive within bucket
    if (threadIdx.x == 255) bsum[blockIdx.x] = s[255];   // bucket total
}

// ---------- phase 3: LDS-staged scatter — bucket-sort in LDS, coalesced burst out ----------
// rec = (row | local<<17, ew); local = col & 255 (8 bits), row < 2^17
__global__ __launch_bounds__(256) void bscatter_kernel(const int* __restrict__ row,
                                                       const int* __restrict__ col,
                                                       const float* __restrict__ ew,
                                                       const int* __restrict__ H,
                                                       const int* __restrict__ bsum,
                                                       int* __restrict__ boff,
                                                       int2* __restrict__ recs) {
    __shared__ int2 lrec[EPB];        // 100 KB: the block's records, bucket-sorted
    __shared__ int  lofs[NB];
    __shared__ int  hcnt[NB];
    __shared__ int  gofs[NB];
    __shared__ int  cur[NB];
    __shared__ int  s[256];
    __shared__ int  carry;
    int tid = threadIdx.x, blk = blockIdx.x;
    if (tid == 0) carry = 0;
    __syncthreads();
    for (int c = 0; c < 2; ++c) {                 // 2*256 >= NB
        int i = c * 256 + tid;
        int v = (i < NB) ? bsum[i] : 0;
        s[tid] = v;
        __syncthreads();
        #pragma unroll
        for (int off = 1; off < 256; off <<= 1) {
            int t = (tid >= off) ? s[tid - off] : 0;
            __syncthreads();
            s[tid] += t;
            __syncthreads();
        }
        if (i < NB) {
            int tb = s[tid] - v + carry;          // bucket start in recs
            int ex = H[i * NBLK + blk];
            gofs[i] = tb + ex;
            hcnt[i] = ((blk < NBLK - 1) ? H[i * NBLK + blk + 1] : v) - ex;
            if (blk == 0) boff[i] = tb;
        }
        __syncthreads();
        if (tid == 0) carry += s[255];
        __syncthreads();
    }
    if (tid == 0) carry = 0;
    __syncthreads();
    for (int c = 0; c < 2; ++c) {
        int i = c * 256 + tid;
        int v = (i < NB) ? hcnt[i] : 0;
        s[tid] = v;
        __syncthreads();
        #pragma unroll
        for (int off = 1; off < 256; off <<= 1) {
            int t = (tid >= off) ? s[tid - off] : 0;
            __syncthreads();
            s[tid] += t;
            __syncthreads();
        }
        if (i < NB) { int l = s[tid] - v + carry; lofs[i] = l; cur[i] = l; }
        __syncthreads();
        if (tid == 0) carry += s[255];
        __syncthreads();
    }
    const int4*   row4 = (const int4*)row;
    const int4*   col4 = (const int4*)col;
    const float4* ew4  = (const float4*)ew;
    int base4 = blk * (EPB / 4);
    for (int j = tid; j < EPB / 4; j += 256) {
        int4   r4 = row4[base4 + j];
        int4   c4 = col4[base4 + j];
        float4 w4 = ew4[base4 + j];
        int p0 = atomicAdd(&cur[c4.x >> 8], 1);
        lrec[p0] = make_int2(r4.x | ((c4.x & 255) << 17), __float_as_int(w4.x));
        int p1 = atomicAdd(&cur[c4.y >> 8], 1);
        lrec[p1] = make_int2(r4.y | ((c4.y & 255) << 17), __float_as_int(w4.y));
        int p2 = atomicAdd(&cur[c4.z >> 8], 1);
        lrec[p2] = make_int2(r4.z | ((c4.z & 255) << 17), __float_as_int(w4.z));
        int p3 = atomicAdd(&cur[c4.w >> 8], 1);
        lrec[p3] = make_int2(r4.w | ((c4.w & 255) << 17), __float_as_int(w4.w));
    }
    __syncthreads();
    int wv = tid >> 6, lane = tid & 63;
    for (int i = wv; i < NB; i += 4) {
        int cnt = hcnt[i], lo = lofs[i], go = gofs[i];
        for (int k = lane; k < cnt; k += 64)
            recs[go + k] = lrec[lo + k];
    }
}

// ---------- phase 3.5: recs pass -> deg+cnt -> dis, rowptr; THEN scale xl in place ----
// tail: yl[n] = dis[n] * xl[n]  (folds dis[row] into the gathered operand)
__global__ __launch_bounds__(256) void degcnt_kernel(const int2* __restrict__ recs,
                                                     const int* __restrict__ boff,
                                                     float* __restrict__ dis,
                                                     int* __restrict__ rowptr,
                                                     ushort_t* xl) {
    __shared__ int   cnt[256];
    __shared__ float degf[256];
    __shared__ int   sscan[256];
    int b = blockIdx.x, tid = threadIdx.x;
    cnt[tid] = 0; degf[tid] = 0.f;
    __syncthreads();
    int s = boff[b], e = (b + 1 < NB) ? boff[b + 1] : N_EDGES;
    for (int j = s + tid; j < e; j += 256) {
        int2 r = recs[j];
        int cl = (r.x >> 17) & 255;
        atomicAdd(&cnt[cl], 1);
        atomicAdd(&degf[cl], __int_as_float(r.y));
    }
    __syncthreads();
    int c = cnt[tid];
    sscan[tid] = c;
    __syncthreads();
    #pragma unroll
    for (int off = 1; off < 256; off <<= 1) {
        int t = (tid >= off) ? sscan[tid - off] : 0;
        __syncthreads();
        sscan[tid] += t;
        __syncthreads();
    }
    rowptr[b * 256 + tid] = s + sscan[tid] - c;   // exclusive; pad nodes get == e
    float d = 1.0f / sqrtf(fmaxf(1.0f + degf[tid], 1e-30f));
    dis[b * 256 + tid] = d;
    __syncthreads();
    degf[tid] = d;                                 // reuse as dis cache for the tail
    __syncthreads();
    // scale tail: yl = dis * xl for this bucket's 256 rows (coalesced uint4)
    int n0 = b * 256;
    for (int i = tid; i < 256 * 8; i += 256) {     // 8 uint4 chunks per 64-ch row
        int r = i >> 3;
        int n = n0 + r;
        if (n >= N_NODES) break;                   // trailing pad rows
        uint4* p = (uint4*)(xl + (size_t)n * HID) + (i & 7);
        float d2 = degf[r];
        uint4 u = *p;
        float lo, hi;
        uint_t w0, w1, w2, w3;
        bf2f2(u.x, lo, hi); w0 = f2bf(lo * d2) | ((uint_t)f2bf(hi * d2) << 16);
        bf2f2(u.y, lo, hi); w1 = f2bf(lo * d2) | ((uint_t)f2bf(hi * d2) << 16);
        bf2f2(u.z, lo, hi); w2 = f2bf(lo * d2) | ((uint_t)f2bf(hi * d2) << 16);
        bf2f2(u.w, lo, hi); w3 = f2bf(lo * d2) | ((uint_t)f2bf(hi * d2) << 16);
        *p = make_uint4(w0, w1, w2, w3);
    }
}

// ---------- phase 4: pure permutation counting-sort scatter (NO dis) ----------
__global__ __launch_bounds__(256) void csrw_kernel(const int2* __restrict__ recs,
                                                   const int* __restrict__ boff,
                                                   const int* __restrict__ rowptr,
                                                   int2* __restrict__ csr) {
    __shared__ int cur[256];
    int b = blockIdx.x, tid = threadIdx.x;
    cur[tid] = rowptr[b * 256 + tid];
    __syncthreads();
    int s = boff[b], e = (b + 1 < NB) ? boff[b + 1] : N_EDGES;
    for (int j = s + tid; j < e; j += 256) {
        int2 r = recs[j];
        int cl = (r.x >> 17) & 255;
        int pos = atomicAdd(&cur[cl], 1);
        csr[pos] = r;                              // gather masks the local bits
    }
}

// ---------- gather core: 8-lane groups, 16B loads, 4 edges in flight/group ----------
// computes yl[n] + sum ew*yl[r]; caller multiplies the reduced result by dis[n].
__device__ __forceinline__ void gather_row(const int2* __restrict__ csr,
                                           const ushort_t* __restrict__ xl,
                                           int base, int end, int n,
                                           int g, int c0,
                                           float4& a0, float4& a1) {
    a0 = make_float4(0.f, 0.f, 0.f, 0.f);
    a1 = make_float4(0.f, 0.f, 0.f, 0.f);
    if (g == 0) {
        ld_bf16x8(xl + (size_t)n * HID + c0, a0, a1);   // self-loop, weight 1
    }
    int j = base + g;
    for (; j + 24 < end; j += 32) {                      // 4 edges in flight
        int2 e0 = csr[j];
        int2 e1 = csr[j + 8];
        int2 e2 = csr[j + 16];
        int2 e3 = csr[j + 24];
        int r0_ = e0.x & 0x1FFFF, r1_ = e1.x & 0x1FFFF;
        int r2_ = e2.x & 0x1FFFF, r3_ = e3.x & 0x1FFFF;
        float w0 = __int_as_float(e0.y), w1 = __int_as_float(e1.y);
        float w2 = __int_as_float(e2.y), w3 = __int_as_float(e3.y);
        float4 xa0, xa1, xb0, xb1, xc0, xc1, xd0, xd1;
        ld_bf16x8(xl + (size_t)r0_ * HID + c0, xa0, xa1);
        ld_bf16x8(xl + (size_t)r1_ * HID + c0, xb0, xb1);
        ld_bf16x8(xl + (size_t)r2_ * HID + c0, xc0, xc1);
        ld_bf16x8(xl + (size_t)r3_ * HID + c0, xd0, xd1);
        a0.x += xa0.x * w0 + xb0.x * w1 + xc0.x * w2 + xd0.x * w3;
        a0.y += xa0.y * w0 + xb0.y * w1 + xc0.y * w2 + xd0.y * w3;
        a0.z += xa0.z * w0 + xb0.z * w1 + xc0.z * w2 + xd0.z * w3;
        a0.w += xa0.w * w0 + xb0.w * w1 + xc0.w * w2 + xd0.w * w3;
        a1.x += xa1.x * w0 + xb1.x * w1 + xc1.x * w2 + xd1.x * w3;
        a1.y += xa1.y * w0 + xb1.y * w1 + xc1.y * w2 + xd1.y * w3;
        a1.z += xa1.z * w0 + xb1.z * w1 + xc1.z * w2 + xd1.z * w3;
        a1.w += xa1.w * w0 + xb1.w * w1 + xc1.w * w2 + xd1.w * w3;
    }
    for (; j < end; j += 8) {
        int2 e0 = csr[j];
        int ra = e0.x & 0x1FFFF;
        float w0 = __int_as_float(e0.y);
        float4 xa0, xa1;
        ld_bf16x8(xl + (size_t)ra * HID + c0, xa0, xa1);
        a0.x += xa0.x * w0; a0.y += xa0.y * w0; a0.z += xa0.z * w0; a0.w += xa0.w * w0;
        a1.x += xa1.x * w0; a1.y += xa1.y * w0; a1.z += xa1.z * w0; a1.w += xa1.w * w0;
    }
    #pragma unroll
    for (int o = 32; o >= 8; o >>= 1) {
        a0.x += __shfl_down(a0.x, o, 64); a0.y += __shfl_down(a0.y, o, 64);
        a0.z += __shfl_down(a0.z, o, 64); a0.w += __shfl_down(a0.w, o, 64);
        a1.x += __shfl_down(a1.x, o, 64); a1.y += __shfl_down(a1.y, o, 64);
        a1.z += __shfl_down(a1.z, o, 64); a1.w += __shfl_down(a1.w, o, 64);
    }
}

// ---------- fused gather1 + gemm2: yl2 = dis * (relu(dis*(...) + b1) @ W2) ----------
__global__ __launch_bounds__(256) void gather_gemm2_kernel(
        const int2* __restrict__ csr, const int* __restrict__ rowptr,
        const float* __restrict__ dis, const ushort_t* __restrict__ xl,
        const float* __restrict__ W2, const float* __restrict__ b1,
        ushort_t* __restrict__ xl2) {
    __shared__ float sW[HID * HID];   // 16 KB
    __shared__ float sh[4][HID];
    __shared__ float sb1[HID];
    int tid = threadIdx.x;
    const float4* W4  = (const float4*)W2;
    float4*       sW4 = (float4*)sW;
    #pragma unroll
    for (int i = 0; i < 4; ++i) sW4[tid + 256 * i] = W4[tid + 256 * i];
    if (tid < HID) sb1[tid] = b1[tid];

    int r0   = blockIdx.x * 4;
    int wv   = tid >> 6;
    int n    = r0 + wv;
    int lane = tid & 63;
    int g    = lane >> 3;
    int c0   = (lane & 7) << 3;
    int base = rowptr[n], end = rowptr[n + 1];
    float d  = dis[n];
    float4 a0, a1;
    gather_row(csr, xl, base, end, n, g, c0, a0, a1);
    if (lane < 8) {
        a0.x *= d; a0.y *= d; a0.z *= d; a0.w *= d;     // apply dis[col]
        a1.x *= d; a1.y *= d; a1.z *= d; a1.w *= d;
        *(float4*)(&sh[wv][c0])     = a0;
        *(float4*)(&sh[wv][c0 + 4]) = a1;
    }
    __syncthreads();
    int lr = wv, cc = lane;
    float hv = fmaxf(sh[lr][cc] + sb1[cc], 0.f);        // relu(agg1 + b1)
    __syncthreads();
    sh[lr][cc] = hv;
    __syncthreads();
    float acc2 = 0.f;
    #pragma unroll 8
    for (int k = 0; k < HID; ++k) acc2 += sh[lr][k] * sW[k * HID + cc];
    xl2[(size_t)(r0 + lr) * HID + cc] = f2bf(acc2 * d); // yl2 = dis * xl2 (out row == n)
}

// ---------- fused gather2 + pool partial: sval[n] = relu(dis*(...)+b2) . Wc ----------
__global__ __launch_bounds__(256) void gather_pool_kernel(
        const int2* __restrict__ csr, const int* __restrict__ rowptr,
        const float* __restrict__ dis, const ushort_t* __restrict__ xl,
        const float* __restrict__ b2, const float* __restrict__ Wc,
        float* __restrict__ sval) {
    int tid  = threadIdx.x;
    int n    = (blockIdx.x * 256 + tid) >> 6;           // grid 25000 exact
    int lane = tid & 63;
    int g    = lane >> 3;
    int c0   = (lane & 7) << 3;
    int base = rowptr[n], end = rowptr[n + 1];
    float d  = dis[n];
    float4 a0, a1;
    gather_row(csr, xl, base, end, n, g, c0, a0, a1);
    if (lane < 8) {
        float4 bb0 = *(const float4*)(b2 + c0);
        float4 bb1 = *(const float4*)(b2 + c0 + 4);
        float4 wc0 = *(const float4*)(Wc + c0);
        float4 wc1 = *(const float4*)(Wc + c0 + 4);
        float s = fmaxf(a0.x * d + bb0.x, 0.f) * wc0.x + fmaxf(a0.y * d + bb0.y, 0.f) * wc0.y
                + fmaxf(a0.z * d + bb0.z, 0.f) * wc0.z + fmaxf(a0.w * d + bb0.w, 0.f) * wc0.w
                + fmaxf(a1.x * d + bb1.x, 0.f) * wc1.x + fmaxf(a1.y * d + bb1.y, 0.f) * wc1.y
                + fmaxf(a1.z * d + bb1.z, 0.f) * wc1.z + fmaxf(a1.w * d + bb1.w, 0.f) * wc1.w;
        s += __shfl_down(s, 4, 64);
        s += __shfl_down(s, 2, 64);
        s += __shfl_down(s, 1, 64);
        if (lane == 0) sval[n] = s;
    }
}

// ---------- final: out[g] = mean(sval over graph range) + bc ----------
__global__ __launch_bounds__(256) void final_out_kernel(const float* __restrict__ sval,
                                                        const int* __restrict__ batch,
                                                        const float* __restrict__ bc,
                                                        float* __restrict__ out) {
    __shared__ float s[256];
    int g = blockIdx.x;   // grid N_GRAPHS
    int lo = 0, hi = N_NODES;
    while (lo < hi) { int m = (lo + hi) >> 1; if (batch[m] < g) lo = m + 1; else hi = m; }
    int start = lo;
    hi = N_NODES;
    while (lo < hi) { int m = (lo + hi) >> 1; if (batch[m] < g + 1) lo = m + 1; else hi = m; }
    int end = lo;
    float acc = 0.f;
    for (int i = start + threadIdx.x; i < end; i += 256) acc += sval[i];
    s[threadIdx.x] = acc;
    __syncthreads();
    #pragma unroll
    for (int off = 128; off > 0; off >>= 1) {
        if (threadIdx.x < off) s[threadIdx.x] += s[threadIdx.x + off];
        __syncthreads();
    }
    if (threadIdx.x == 0)
        out[g] = s[0] / fmaxf((float)(end - start), 1.0f) + bc[0];
}

extern "C" void kernel_launch(void* const* d_in, const int* in_sizes, int n_in,
                              void* d_out, int out_size, void* d_ws, size_t ws_size,
                              hipStream_t stream) {
    const float* x     = (const float*)d_in[0];
    const int*   ei    = (const int*)  d_in[1];
    const float* ew    = (const float*)d_in[2];
    const int*   batch = (const int*)  d_in[3];
    const float* W1    = (const float*)d_in[4];
    const float* b1    = (const float*)d_in[5];
    const float* W2    = (const float*)d_in[6];
    const float* b2    = (const float*)d_in[7];
    const float* Wc    = (const float*)d_in[8];
    const float* bc    = (const float*)d_in[9];
    float* out = (float*)d_out;

    const int* row = ei;
    const int* col = ei + N_EDGES;

    // workspace (~78 MB): recs | xlA | xlB | csr | rowptr | dis | bsum | boff | sval
    // H aliases csr (dead before csrw writes csr).
    int2*     recs   = (int2*)d_ws;                              // E int2 = 25.6 MB
    ushort_t* xlA    = (ushort_t*)(recs + N_EDGES);              // N*HID bf16
    ushort_t* xlB    = xlA + (size_t)N_NODES * HID;              // N*HID bf16
    int2*     csr    = (int2*)(xlB + (size_t)N_NODES * HID);     // E int2
    int*      rowptr = (int*)(csr + N_EDGES);                    // N_PAD
    float*    dis    = (float*)(rowptr + N_PAD);                 // N_PAD
    int*      bsum   = (int*)(dis + N_PAD);                      // 512
    int*      boff   = bsum + 512;                               // 512
    float*    sval   = (float*)(boff + 512);                     // N_PAD
    int*      H      = (int*)csr;                                // NB*NBLK ints = 401 KB

    bhist_gemm1_kernel<<<NBLK + G1BLK, 256, 0, stream>>>(col, H, x, W1, xlA);
    scan1_kernel    <<<NB,   256, 0, stream>>>(H, bsum);
    bscatter_kernel <<<NBLK, 256, 0, stream>>>(row, col, ew, H, bsum, boff, recs);
    degcnt_kernel   <<<NB,   256, 0, stream>>>(recs, boff, dis, rowptr, xlA);
    csrw_kernel     <<<NB,   256, 0, stream>>>(recs, boff, rowptr, csr);
    gather_gemm2_kernel<<<N_NODES / 4, 256, 0, stream>>>(csr, rowptr, dis, xlA, W2, b1, xlB);
    gather_pool_kernel <<<N_NODES / 4, 256, 0, stream>>>(csr, rowptr, dis, xlB, b2, Wc, sval);
    final_out_kernel<<<N_GRAPHS, 256, 0, stream>>>(sval, batch, bc, out);
}

// Round 16
// 442.671 us; speedup vs baseline: 1.0721x; 1.0084x over previous
//
#include <hip/hip_runtime.h>

#define N_NODES 100000
#define N_PAD   100352        // 392*256
#define N_EDGES 3200000
#define IN_DIM  128
#define HID     64
#define N_GRAPHS 256
#define NB      392           // buckets of 256 dest nodes each
#define NBLK    256           // hist/scatter blocks
#define EPB     (N_EDGES / NBLK)   // 12500
#define G1BLK   (N_NODES / 8)      // 12500 gemm1 blocks

typedef unsigned short ushort_t;
typedef unsigned int   uint_t;

// bf16 helpers: storage-only compression of the gathered operand
__device__ __forceinline__ ushort_t f2bf(float v) {          // round-to-nearest-even
    uint_t b = __float_as_uint(v);
    b += 0x7fffu + ((b >> 16) & 1u);
    return (ushort_t)(b >> 16);
}
__device__ __forceinline__ void bf2f2(uint_t u, float& lo, float& hi) {
    lo = __uint_as_float(u << 16);
    hi = __uint_as_float(u & 0xffff0000u);
}
// 16B load -> 8 floats
__device__ __forceinline__ void ld_bf16x8(const ushort_t* p, float4& a, float4& b) {
    uint4 u = *(const uint4*)p;
    bf2f2(u.x, a.x, a.y); bf2f2(u.y, a.z, a.w);
    bf2f2(u.z, b.x, b.y); bf2f2(u.w, b.z, b.w);
}

// ---------- phase 1 (fused): bucket histogram (blocks 0..NBLK-1) + gemm1 (rest) ----------
__global__ __launch_bounds__(256) void bhist_gemm1_kernel(
        const int* __restrict__ col, int* __restrict__ H,
        const float* __restrict__ x, const float* __restrict__ W1,
        ushort_t* __restrict__ xl) {
    __shared__ int   h[2][NB];           // 3.1 KB
    __shared__ float sW[IN_DIM * HID];   // 32 KB
    __shared__ float sx[8][IN_DIM];      // 4 KB  (union 39 KB -> 4 blocks/CU)
    int tid = threadIdx.x;
    if (blockIdx.x < NBLK) {
        for (int i = tid; i < NB; i += 256) { h[0][i] = 0; h[1][i] = 0; }
        __syncthreads();
        const int4* col4 = (const int4*)col;
        int base4 = blockIdx.x * (EPB / 4);
        int sel = tid & 1;
        for (int j = tid; j < EPB / 4; j += 256) {
            int4 c = col4[base4 + j];
            atomicAdd(&h[sel][c.x >> 8], 1);
            atomicAdd(&h[sel][c.y >> 8], 1);
            atomicAdd(&h[sel][c.z >> 8], 1);
            atomicAdd(&h[sel][c.w >> 8], 1);
        }
        __syncthreads();
        for (int i = tid; i < NB; i += 256) H[i * NBLK + blockIdx.x] = h[0][i] + h[1][i];
    } else {
        int bid = blockIdx.x - NBLK;
        const float4* W4  = (const float4*)W1;
        float4*       sW4 = (float4*)sW;
        #pragma unroll
        for (int i = 0; i < 8; ++i) sW4[tid + 256 * i] = W4[tid + 256 * i];
        int r0 = bid * 8;
        const float4* x4  = (const float4*)(x + (size_t)r0 * IN_DIM);
        float4*       sx4 = (float4*)&sx[0][0];
        sx4[tid] = x4[tid];              // 256 float4 = 8 rows x 128
        __syncthreads();
        int c = tid & 63;
        #pragma unroll
        for (int rep = 0; rep < 2; ++rep) {
            int lr = (tid >> 6) * 2 + rep;   // 0..7
            float acc = 0.f;
            #pragma unroll 8
            for (int k = 0; k < IN_DIM; ++k) acc += sx[lr][k] * sW[k * HID + c];
            xl[(size_t)(r0 + lr) * HID + c] = f2bf(acc);
        }
    }
}

// ---------- phase 2: exclusive scan of H (NB*NBLK, bucket-major) ----------
__global__ __launch_bounds__(256) void scan1_kernel(int* H, int* __restrict__ bsum) {
    __shared__ int s[256];
    int i = blockIdx.x * 256 + threadIdx.x;   // blockIdx.x == bucket (NBLK==256)
    int v = H[i];
    s[threadIdx.x] = v;
    __syncthreads();
    #pragma unroll
    for (int off = 1; off < 256; off <<= 1) {
        int t = (threadIdx.x >= off) ? s[threadIdx.x - off] : 0;
        __syncthreads();
        s[threadIdx.x] += t;
        __syncthreads();
    }
    H[i] = s[threadIdx.x] - v;                           // exclusive within bucket
    if (threadIdx.x == 255) bsum[blockIdx.x] = s[255];   // bucket total
}

// ---------- phase 3: LDS-staged scatter — bucket-sort in LDS, coalesced burst out ----------
// rec = (row | local<<17, ew); local = col & 255 (8 bits), row < 2^17
__global__ __launch_bounds__(256) void bscatter_kernel(const int* __restrict__ row,
                                                       const int* __restrict__ col,
                                                       const float* __restrict__ ew,
                                                       const int* __restrict__ H,
                                                       const int* __restrict__ bsum,
                                                       int* __restrict__ boff,
                                                       int2* __restrict__ recs) {
    __shared__ int2 lrec[EPB];        // 100 KB: the block's records, bucket-sorted
    __shared__ int  lofs[NB];
    __shared__ int  hcnt[NB];
    __shared__ int  gofs[NB];
    __shared__ int  cur[NB];
    __shared__ int  s[256];
    __shared__ int  carry;
    int tid = threadIdx.x, blk = blockIdx.x;
    if (tid == 0) carry = 0;
    __syncthreads();
    for (int c = 0; c < 2; ++c) {                 // 2*256 >= NB
        int i = c * 256 + tid;
        int v = (i < NB) ? bsum[i] : 0;
        s[tid] = v;
        __syncthreads();
        #pragma unroll
        for (int off = 1; off < 256; off <<= 1) {
            int t = (tid >= off) ? s[tid - off] : 0;
            __syncthreads();
            s[tid] += t;
            __syncthreads();
        }
        if (i < NB) {
            int tb = s[tid] - v + carry;          // bucket start in recs
            int ex = H[i * NBLK + blk];
            gofs[i] = tb + ex;
            hcnt[i] = ((blk < NBLK - 1) ? H[i * NBLK + blk + 1] : v) - ex;
            if (blk == 0) boff[i] = tb;
        }
        __syncthreads();
        if (tid == 0) carry += s[255];
        __syncthreads();
    }
    if (tid == 0) carry = 0;
    __syncthreads();
    for (int c = 0; c < 2; ++c) {
        int i = c * 256 + tid;
        int v = (i < NB) ? hcnt[i] : 0;
        s[tid] = v;
        __syncthreads();
        #pragma unroll
        for (int off = 1; off < 256; off <<= 1) {
            int t = (tid >= off) ? s[tid - off] : 0;
            __syncthreads();
            s[tid] += t;
            __syncthreads();
        }
        if (i < NB) { int l = s[tid] - v + carry; lofs[i] = l; cur[i] = l; }
        __syncthreads();
        if (tid == 0) carry += s[255];
        __syncthreads();
    }
    const int4*   row4 = (const int4*)row;
    const int4*   col4 = (const int4*)col;
    const float4* ew4  = (const float4*)ew;
    int base4 = blk * (EPB / 4);
    for (int j = tid; j < EPB / 4; j += 256) {
        int4   r4 = row4[base4 + j];
        int4   c4 = col4[base4 + j];
        float4 w4 = ew4[base4 + j];
        int p0 = atomicAdd(&cur[c4.x >> 8], 1);
        lrec[p0] = make_int2(r4.x | ((c4.x & 255) << 17), __float_as_int(w4.x));
        int p1 = atomicAdd(&cur[c4.y >> 8], 1);
        lrec[p1] = make_int2(r4.y | ((c4.y & 255) << 17), __float_as_int(w4.y));
        int p2 = atomicAdd(&cur[c4.z >> 8], 1);
        lrec[p2] = make_int2(r4.z | ((c4.z & 255) << 17), __float_as_int(w4.z));
        int p3 = atomicAdd(&cur[c4.w >> 8], 1);
        lrec[p3] = make_int2(r4.w | ((c4.w & 255) << 17), __float_as_int(w4.w));
    }
    __syncthreads();
    int wv = tid >> 6, lane = tid & 63;
    for (int i = wv; i < NB; i += 4) {
        int cnt = hcnt[i], lo = lofs[i], go = gofs[i];
        for (int k = lane; k < cnt; k += 64)
            recs[go + k] = lrec[lo + k];
    }
}

// ---------- phase 3.5 (fused): recs pass -> deg+cnt -> dis/rowptr -> csr permutation
// scatter (L2-warm) -> yl scale tail. All block-local after R15's factorization.
__global__ __launch_bounds__(256) void degcsr_kernel(const int2* __restrict__ recs,
                                                     const int* __restrict__ boff,
                                                     float* __restrict__ dis,
                                                     int* __restrict__ rowptr,
                                                     int2* __restrict__ csr,
                                                     ushort_t* xl) {
    __shared__ int   cnt[256];
    __shared__ float degf[256];
    __shared__ int   sscan[256];
    __shared__ int   cur[256];
    int b = blockIdx.x, tid = threadIdx.x;
    cnt[tid] = 0; degf[tid] = 0.f;
    __syncthreads();
    int s = boff[b], e = (b + 1 < NB) ? boff[b + 1] : N_EDGES;
    for (int j = s + tid; j < e; j += 256) {
        int2 r = recs[j];
        int cl = (r.x >> 17) & 255;
        atomicAdd(&cnt[cl], 1);
        atomicAdd(&degf[cl], __int_as_float(r.y));
    }
    __syncthreads();
    int c = cnt[tid];
    sscan[tid] = c;
    __syncthreads();
    #pragma unroll
    for (int off = 1; off < 256; off <<= 1) {
        int t = (tid >= off) ? sscan[tid - off] : 0;
        __syncthreads();
        sscan[tid] += t;
        __syncthreads();
    }
    int rp = s + sscan[tid] - c;                  // exclusive; pad nodes get == e
    rowptr[b * 256 + tid] = rp;
    cur[tid] = rp;
    float d = 1.0f / sqrtf(fmaxf(1.0f + degf[tid], 1e-30f));
    dis[b * 256 + tid] = d;
    __syncthreads();
    degf[tid] = d;                                // reuse as dis cache for the tail
    __syncthreads();
    // csr permutation scatter (bucket's recs are L2-warm from pass 1)
    for (int j = s + tid; j < e; j += 256) {
        int2 r = recs[j];
        int cl = (r.x >> 17) & 255;
        int pos = atomicAdd(&cur[cl], 1);
        csr[pos] = r;                             // gather masks the local bits
    }
    // scale tail: yl = dis * xl for this bucket's 256 rows (coalesced uint4)
    int n0 = b * 256;
    for (int i = tid; i < 256 * 8; i += 256) {    // 8 uint4 chunks per 64-ch row
        int r = i >> 3;
        int n = n0 + r;
        if (n >= N_NODES) break;                  // trailing pad rows
        uint4* p = (uint4*)(xl + (size_t)n * HID) + (i & 7);
        float d2 = degf[r];
        uint4 u = *p;
        float lo, hi;
        uint_t w0, w1, w2, w3;
        bf2f2(u.x, lo, hi); w0 = f2bf(lo * d2) | ((uint_t)f2bf(hi * d2) << 16);
        bf2f2(u.y, lo, hi); w1 = f2bf(lo * d2) | ((uint_t)f2bf(hi * d2) << 16);
        bf2f2(u.z, lo, hi); w2 = f2bf(lo * d2) | ((uint_t)f2bf(hi * d2) << 16);
        bf2f2(u.w, lo, hi); w3 = f2bf(lo * d2) | ((uint_t)f2bf(hi * d2) << 16);
        *p = make_uint4(w0, w1, w2, w3);
    }
}

// ---------- gather core: 8-lane groups, 16B loads, 4 edges in flight/group ----------
// computes yl[n] + sum ew*yl[r]; caller multiplies the reduced result by dis[n].
__device__ __forceinline__ void gather_row(const int2* __restrict__ csr,
                                           const ushort_t* __restrict__ xl,
                                           int base, int end, int n,
                                           int g, int c0,
                                           float4& a0, float4& a1) {
    a0 = make_float4(0.f, 0.f, 0.f, 0.f);
    a1 = make_float4(0.f, 0.f, 0.f, 0.f);
    if (g == 0) {
        ld_bf16x8(xl + (size_t)n * HID + c0, a0, a1);   // self-loop, weight 1
    }
    int j = base + g;
    for (; j + 24 < end; j += 32) {                      // 4 edges in flight
        int2 e0 = csr[j];
        int2 e1 = csr[j + 8];
        int2 e2 = csr[j + 16];
        int2 e3 = csr[j + 24];
        int r0_ = e0.x & 0x1FFFF, r1_ = e1.x & 0x1FFFF;
        int r2_ = e2.x & 0x1FFFF, r3_ = e3.x & 0x1FFFF;
        float w0 = __int_as_float(e0.y), w1 = __int_as_float(e1.y);
        float w2 = __int_as_float(e2.y), w3 = __int_as_float(e3.y);
        float4 xa0, xa1, xb0, xb1, xc0, xc1, xd0, xd1;
        ld_bf16x8(xl + (size_t)r0_ * HID + c0, xa0, xa1);
        ld_bf16x8(xl + (size_t)r1_ * HID + c0, xb0, xb1);
        ld_bf16x8(xl + (size_t)r2_ * HID + c0, xc0, xc1);
        ld_bf16x8(xl + (size_t)r3_ * HID + c0, xd0, xd1);
        a0.x += xa0.x * w0 + xb0.x * w1 + xc0.x * w2 + xd0.x * w3;
        a0.y += xa0.y * w0 + xb0.y * w1 + xc0.y * w2 + xd0.y * w3;
        a0.z += xa0.z * w0 + xb0.z * w1 + xc0.z * w2 + xd0.z * w3;
        a0.w += xa0.w * w0 + xb0.w * w1 + xc0.w * w2 + xd0.w * w3;
        a1.x += xa1.x * w0 + xb1.x * w1 + xc1.x * w2 + xd1.x * w3;
        a1.y += xa1.y * w0 + xb1.y * w1 + xc1.y * w2 + xd1.y * w3;
        a1.z += xa1.z * w0 + xb1.z * w1 + xc1.z * w2 + xd1.z * w3;
        a1.w += xa1.w * w0 + xb1.w * w1 + xc1.w * w2 + xd1.w * w3;
    }
    for (; j < end; j += 8) {
        int2 e0 = csr[j];
        int ra = e0.x & 0x1FFFF;
        float w0 = __int_as_float(e0.y);
        float4 xa0, xa1;
        ld_bf16x8(xl + (size_t)ra * HID + c0, xa0, xa1);
        a0.x += xa0.x * w0; a0.y += xa0.y * w0; a0.z += xa0.z * w0; a0.w += xa0.w * w0;
        a1.x += xa1.x * w0; a1.y += xa1.y * w0; a1.z += xa1.z * w0; a1.w += xa1.w * w0;
    }
    #pragma unroll
    for (int o = 32; o >= 8; o >>= 1) {
        a0.x += __shfl_down(a0.x, o, 64); a0.y += __shfl_down(a0.y, o, 64);
        a0.z += __shfl_down(a0.z, o, 64); a0.w += __shfl_down(a0.w, o, 64);
        a1.x += __shfl_down(a1.x, o, 64); a1.y += __shfl_down(a1.y, o, 64);
        a1.z += __shfl_down(a1.z, o, 64); a1.w += __shfl_down(a1.w, o, 64);
    }
}

// ---------- fused gather1 + gemm2: yl2 = dis * (relu(dis*(...) + b1) @ W2) ----------
__global__ __launch_bounds__(256) void gather_gemm2_kernel(
        const int2* __restrict__ csr, const int* __restrict__ rowptr,
        const float* __restrict__ dis, const ushort_t* __restrict__ xl,
        const float* __restrict__ W2, const float* __restrict__ b1,
        ushort_t* __restrict__ xl2) {
    __shared__ float sW[HID * HID];   // 16 KB
    __shared__ float sh[4][HID];
    __shared__ float sb1[HID];
    int tid = threadIdx.x;
    const float4* W4  = (const float4*)W2;
    float4*       sW4 = (float4*)sW;
    #pragma unroll
    for (int i = 0; i < 4; ++i) sW4[tid + 256 * i] = W4[tid + 256 * i];
    if (tid < HID) sb1[tid] = b1[tid];

    int r0   = blockIdx.x * 4;
    int wv   = tid >> 6;
    int n    = r0 + wv;
    int lane = tid & 63;
    int g    = lane >> 3;
    int c0   = (lane & 7) << 3;
    int base = rowptr[n], end = rowptr[n + 1];
    float d  = dis[n];
    float4 a0, a1;
    gather_row(csr, xl, base, end, n, g, c0, a0, a1);
    if (lane < 8) {
        a0.x *= d; a0.y *= d; a0.z *= d; a0.w *= d;     // apply dis[col]
        a1.x *= d; a1.y *= d; a1.z *= d; a1.w *= d;
        *(float4*)(&sh[wv][c0])     = a0;
        *(float4*)(&sh[wv][c0 + 4]) = a1;
    }
    __syncthreads();
    int lr = wv, cc = lane;
    float hv = fmaxf(sh[lr][cc] + sb1[cc], 0.f);        // relu(agg1 + b1)
    __syncthreads();
    sh[lr][cc] = hv;
    __syncthreads();
    float acc2 = 0.f;
    #pragma unroll 8
    for (int k = 0; k < HID; ++k) acc2 += sh[lr][k] * sW[k * HID + cc];
    xl2[(size_t)(r0 + lr) * HID + cc] = f2bf(acc2 * d); // yl2 = dis * xl2 (out row == n)
}

// ---------- fused gather2 + pool partial: sval[n] = relu(dis*(...)+b2) . Wc ----------
__global__ __launch_bounds__(256) void gather_pool_kernel(
        const int2* __restrict__ csr, const int* __restrict__ rowptr,
        const float* __restrict__ dis, const ushort_t* __restrict__ xl,
        const float* __restrict__ b2, const float* __restrict__ Wc,
        float* __restrict__ sval) {
    int tid  = threadIdx.x;
    int n    = (blockIdx.x * 256 + tid) >> 6;           // grid 25000 exact
    int lane = tid & 63;
    int g    = lane >> 3;
    int c0   = (lane & 7) << 3;
    int base = rowptr[n], end = rowptr[n + 1];
    float d  = dis[n];
    float4 a0, a1;
    gather_row(csr, xl, base, end, n, g, c0, a0, a1);
    if (lane < 8) {
        float4 bb0 = *(const float4*)(b2 + c0);
        float4 bb1 = *(const float4*)(b2 + c0 + 4);
        float4 wc0 = *(const float4*)(Wc + c0);
        float4 wc1 = *(const float4*)(Wc + c0 + 4);
        float s = fmaxf(a0.x * d + bb0.x, 0.f) * wc0.x + fmaxf(a0.y * d + bb0.y, 0.f) * wc0.y
                + fmaxf(a0.z * d + bb0.z, 0.f) * wc0.z + fmaxf(a0.w * d + bb0.w, 0.f) * wc0.w
                + fmaxf(a1.x * d + bb1.x, 0.f) * wc1.x + fmaxf(a1.y * d + bb1.y, 0.f) * wc1.y
                + fmaxf(a1.z * d + bb1.z, 0.f) * wc1.z + fmaxf(a1.w * d + bb1.w, 0.f) * wc1.w;
        s += __shfl_down(s, 4, 64);
        s += __shfl_down(s, 2, 64);
        s += __shfl_down(s, 1, 64);
        if (lane == 0) sval[n] = s;
    }
}

// ---------- final: out[g] = mean(sval over graph range) + bc ----------
__global__ __launch_bounds__(256) void final_out_kernel(const float* __restrict__ sval,
                                                        const int* __restrict__ batch,
                                                        const float* __restrict__ bc,
                                                        float* __restrict__ out) {
    __shared__ float s[256];
    int g = blockIdx.x;   // grid N_GRAPHS
    int lo = 0, hi = N_NODES;
    while (lo < hi) { int m = (lo + hi) >> 1; if (batch[m] < g) lo = m + 1; else hi = m; }
    int start = lo;
    hi = N_NODES;
    while (lo < hi) { int m = (lo + hi) >> 1; if (batch[m] < g + 1) lo = m + 1; else hi = m; }
    int end = lo;
    float acc = 0.f;
    for (int i = start + threadIdx.x; i < end; i += 256) acc += sval[i];
    s[threadIdx.x] = acc;
    __syncthreads();
    #pragma unroll
    for (int off = 128; off > 0; off >>= 1) {
        if (threadIdx.x < off) s[threadIdx.x] += s[threadIdx.x + off];
        __syncthreads();
    }
    if (threadIdx.x == 0)
        out[g] = s[0] / fmaxf((float)(end - start), 1.0f) + bc[0];
}

extern "C" void kernel_launch(void* const* d_in, const int* in_sizes, int n_in,
                              void* d_out, int out_size, void* d_ws, size_t ws_size,
                              hipStream_t stream) {
    const float* x     = (const float*)d_in[0];
    const int*   ei    = (const int*)  d_in[1];
    const float* ew    = (const float*)d_in[2];
    const int*   batch = (const int*)  d_in[3];
    const float* W1    = (const float*)d_in[4];
    const float* b1    = (const float*)d_in[5];
    const float* W2    = (const float*)d_in[6];
    const float* b2    = (const float*)d_in[7];
    const float* Wc    = (const float*)d_in[8];
    const float* bc    = (const float*)d_in[9];
    float* out = (float*)d_out;

    const int* row = ei;
    const int* col = ei + N_EDGES;

    // workspace (~78 MB): recs | xlA | xlB | csr | rowptr | dis | bsum | boff | sval
    // H aliases csr (dead before degcsr writes csr).
    int2*     recs   = (int2*)d_ws;                              // E int2 = 25.6 MB
    ushort_t* xlA    = (ushort_t*)(recs + N_EDGES);              // N*HID bf16
    ushort_t* xlB    = xlA + (size_t)N_NODES * HID;              // N*HID bf16
    int2*     csr    = (int2*)(xlB + (size_t)N_NODES * HID);     // E int2
    int*      rowptr = (int*)(csr + N_EDGES);                    // N_PAD
    float*    dis    = (float*)(rowptr + N_PAD);                 // N_PAD
    int*      bsum   = (int*)(dis + N_PAD);                      // 512
    int*      boff   = bsum + 512;                               // 512
    float*    sval   = (float*)(boff + 512);                     // N_PAD
    int*      H      = (int*)csr;                                // NB*NBLK ints = 401 KB

    bhist_gemm1_kernel<<<NBLK + G1BLK, 256, 0, stream>>>(col, H, x, W1, xlA);
    scan1_kernel    <<<NB,   256, 0, stream>>>(H, bsum);
    bscatter_kernel <<<NBLK, 256, 0, stream>>>(row, col, ew, H, bsum, boff, recs);
    degcsr_kernel   <<<NB,   256, 0, stream>>>(recs, boff, dis, rowptr, csr, xlA);
    gather_gemm2_kernel<<<N_NODES / 4, 256, 0, stream>>>(csr, rowptr, dis, xlA, W2, b1, xlB);
    gather_pool_kernel <<<N_NODES / 4, 256, 0, stream>>>(csr, rowptr, dis, xlB, b2, Wc, sval);
    final_out_kernel<<<N_GRAPHS, 256, 0, stream>>>(sval, batch, bc, out);
}